// Round 3
// baseline (1714.198 us; speedup 1.0000x reference)
//
#include <hip/hip_runtime.h>
#include <hip/hip_bf16.h>
#include <math.h>

// ---------------------------------------------------------------------------
// LinearTransformerCausalDecoder on MI355X (gfx950)
// B=2, S=M=1024, D=512, H=8, HD=64, L=4, FF=2048
// All d_in / d_out are FLOAT32 (per reference dtypes). Internal attn/ffh
// activations stored bf16 (consumed only as bf16 MFMA A-operands).
// Workspace ~30.3 MB.
// ---------------------------------------------------------------------------

typedef unsigned short u16;
typedef __bf16 bf16x8 __attribute__((ext_vector_type(8)));
typedef float f32x4v __attribute__((ext_vector_type(4)));

#define DEVI __device__ __forceinline__

DEVI float bf2f(u16 u) { return __uint_as_float(((unsigned)u) << 16); }
DEVI u16 f2bf(float f) {
  unsigned u = __float_as_uint(f);
  u += 0x7FFFu + ((u >> 16) & 1u);   // RNE
  return (u16)(u >> 16);
}

// ---------------------------------------------------------------------------
// GEMM: C[M][N] = act(A[M][K] @ W[K][N] + bias), W f32 in natural [K][N]
// layout (bf16 convert + transpose happen in the LDS write). BM=128, BK=32,
// 4 waves (2x2), mfma_f32_16x16x32_bf16.
// ACT: 0 none, 1 phi=elu+1, 2 gelu(exact)
// ADT: 0 A=f32, 1 A=bf16      CDT: 0 C=f32, 1 C=bf16
// ---------------------------------------------------------------------------
template<int BN, int ACT, int ADT, int CDT>
__global__ __launch_bounds__(256) void gemm_kernel(
    const void* __restrict__ Av, const float* __restrict__ W,
    const float* __restrict__ bias, void* __restrict__ Cv,
    int M, int N, int K)
{
  constexpr int BM = 128, BK = 32, LDT = 40;   // 80B row stride: 16B-aligned
  __shared__ __align__(16) u16 As[BM * LDT];
  __shared__ __align__(16) u16 Bs[BN * LDT];
  const int tid = threadIdx.x;
  const int bm0 = blockIdx.x * BM, bn0 = blockIdx.y * BN;
  const int lane = tid & 63, wid = tid >> 6;
  const int wr = wid >> 1, wc = wid & 1;       // 2x2 wave grid
  constexpr int WN = BN / 2, NM = 4, NN = WN / 16;
  const int l15 = lane & 15, lg = lane >> 4;
  f32x4v acc[NM][NN] = {};

  for (int k0 = 0; k0 < K; k0 += BK) {
    // ---- stage A tile 128x32 into As[m][k] (bf16) ----
    if (ADT == 0) {
      const float* A = (const float*)Av;
#pragma unroll
      for (int p = 0; p < 4; ++p) {
        const int row = (tid >> 3) + p * 32;
        const int kg = tid & 7;
        const float4 v = *(const float4*)&A[(size_t)(bm0 + row) * K + k0 + kg * 4];
        *(ushort4*)&As[row * LDT + kg * 4] =
            make_ushort4(f2bf(v.x), f2bf(v.y), f2bf(v.z), f2bf(v.w));
      }
    } else {
      const u16* A = (const u16*)Av;
#pragma unroll
      for (int p = 0; p < 2; ++p) {
        const int e = tid + p * 256;
        const int row = e >> 2, q = e & 3;
        *(uint4*)&As[row * LDT + q * 8] =
            *(const uint4*)&A[(size_t)(bm0 + row) * K + k0 + q * 8];
      }
    }
    // ---- stage W tile 32xBN (f32), convert + transpose into Bs[n][k] ----
    {
      const int kp = tid >> 4, nq = tid & 15;    // kp: k-pair 0..15, nq: n-quad
#pragma unroll
      for (int pp = 0; pp < BN / 64; ++pp) {
        const int nb = pp * 64 + nq * 4;
        const float4 a = *(const float4*)&W[(size_t)(k0 + 2 * kp) * N + bn0 + nb];
        const float4 b = *(const float4*)&W[(size_t)(k0 + 2 * kp + 1) * N + bn0 + nb];
        *(unsigned*)&Bs[(nb + 0) * LDT + 2 * kp] = (unsigned)f2bf(a.x) | ((unsigned)f2bf(b.x) << 16);
        *(unsigned*)&Bs[(nb + 1) * LDT + 2 * kp] = (unsigned)f2bf(a.y) | ((unsigned)f2bf(b.y) << 16);
        *(unsigned*)&Bs[(nb + 2) * LDT + 2 * kp] = (unsigned)f2bf(a.z) | ((unsigned)f2bf(b.z) << 16);
        *(unsigned*)&Bs[(nb + 3) * LDT + 2 * kp] = (unsigned)f2bf(a.w) | ((unsigned)f2bf(b.w) << 16);
      }
    }
    __syncthreads();
    bf16x8 af[NM], bfv[NN];
#pragma unroll
    for (int mm = 0; mm < NM; ++mm)
      af[mm] = *(const bf16x8*)&As[(wr * 64 + mm * 16 + l15) * LDT + lg * 8];
#pragma unroll
    for (int nn = 0; nn < NN; ++nn)
      bfv[nn] = *(const bf16x8*)&Bs[(wc * WN + nn * 16 + l15) * LDT + lg * 8];
#pragma unroll
    for (int mm = 0; mm < NM; ++mm)
#pragma unroll
      for (int nn = 0; nn < NN; ++nn)
        acc[mm][nn] = __builtin_amdgcn_mfma_f32_16x16x32_bf16(af[mm], bfv[nn], acc[mm][nn], 0, 0, 0);
    __syncthreads();
  }
  // epilogue: D mapping col=lane&15, row=(lane>>4)*4+r
#pragma unroll
  for (int nn = 0; nn < NN; ++nn) {
    const int col = bn0 + wc * WN + nn * 16 + l15;
    const float bv = bias[col];
#pragma unroll
    for (int mm = 0; mm < NM; ++mm) {
#pragma unroll
      for (int r = 0; r < 4; ++r) {
        const int row = bm0 + wr * 64 + mm * 16 + lg * 4 + r;
        float v = acc[mm][nn][r] + bv;
        if (ACT == 1) v = v > 0.f ? v + 1.f : __expf(v);
        if (ACT == 2) v = 0.5f * v * (1.f + erff(v * 0.70710678f));
        if (CDT == 0) ((float*)Cv)[(size_t)row * N + col] = v;
        else          ((u16*)Cv)[(size_t)row * N + col] = f2bf(v);
      }
    }
  }
}

// ---------------------------------------------------------------------------
// Linear attention chunk sums: per (chunk c, b, h):
//   KVc[bh][c][d][m] = sum_{s in chunk} k[s][d] * v[s][m],  zc = sum k
// ---------------------------------------------------------------------------
__global__ __launch_bounds__(256) void lin_chunk_sums(
    const float* __restrict__ kbuf, const float* __restrict__ vbuf,
    float* __restrict__ KVc, float* __restrict__ zc)
{
  __shared__ __align__(16) float ks[64 * 68];
  __shared__ __align__(16) float vs[64 * 68];
  const int c = blockIdx.x, bh = blockIdx.y;
  const int b = bh >> 3, h = bh & 7;
  const int t = threadIdx.x;
  const size_t rowbase = (size_t)(b * 1024 + c * 64);
  {
    const int s = t >> 2, dg = t & 3;
#pragma unroll
    for (int ii = 0; ii < 4; ++ii) {
      const int d = dg * 16 + ii * 4;
      *(float4*)&ks[s * 68 + d] = *(const float4*)&kbuf[(rowbase + s) * 512 + h * 64 + d];
      *(float4*)&vs[s * 68 + d] = *(const float4*)&vbuf[(rowbase + s) * 512 + h * 64 + d];
    }
  }
  __syncthreads();
  const int m = t & 63, ig = t >> 6;
  float acc[16] = {};
  for (int ss = 0; ss < 64; ++ss) {
    const float vv = vs[ss * 68 + m];
#pragma unroll
    for (int i = 0; i < 16; i += 4) {
      float4 kk = *(const float4*)&ks[ss * 68 + ig * 16 + i];
      acc[i]     += kk.x * vv; acc[i + 1] += kk.y * vv;
      acc[i + 2] += kk.z * vv; acc[i + 3] += kk.w * vv;
    }
  }
  float* kvout = KVc + (size_t)(bh * 16 + c) * 4096;
#pragma unroll
  for (int i = 0; i < 16; ++i) kvout[(ig * 16 + i) * 64 + m] = acc[i];
  if (t < 64) {
    float z = 0.f;
    for (int ss = 0; ss < 64; ++ss) z += ks[ss * 68 + t];
    zc[(size_t)(bh * 16 + c) * 64 + t] = z;
  }
}

// exclusive prefix over the 16 chunks, per cell.  grid (grp=16, bh=16)
__global__ __launch_bounds__(256) void lin_scan_exclusive(
    float* __restrict__ KVc, float* __restrict__ zc)
{
  const int grp = blockIdx.x, bh = blockIdx.y, t = threadIdx.x;
  const size_t base = (size_t)bh * 16 * 4096 + grp * 256 + t;
  float run = 0.f;
#pragma unroll
  for (int c = 0; c < 16; ++c) {
    const float tmp = KVc[base + (size_t)c * 4096];
    KVc[base + (size_t)c * 4096] = run;
    run += tmp;
  }
  if (grp == 0 && t < 64) {
    const size_t zb = (size_t)bh * 16 * 64 + t;
    float rz = 0.f;
#pragma unroll
    for (int c = 0; c < 16; ++c) {
      const float tmp = zc[zb + c * 64];
      zc[zb + c * 64] = rz;
      rz += tmp;
    }
  }
}

// ---------------------------------------------------------------------------
// SA apply: out = (intra-chunk masked QK^T V + Q @ KV_prefix) / (den + eps)
// out written bf16.  grid (c=16, bh=16); row i = t&63, m-group mg = t>>6.
// ---------------------------------------------------------------------------
__global__ __launch_bounds__(256) void sa_apply(
    const float* __restrict__ qbuf, const float* __restrict__ kbuf,
    const float* __restrict__ vbuf, const float* __restrict__ KVc,
    const float* __restrict__ zc, u16* __restrict__ out)
{
  __shared__ __align__(16) float ks[64 * 68];
  __shared__ __align__(16) float vs[64 * 68];
  __shared__ float zp[64];
  const int c = blockIdx.x, bh = blockIdx.y;
  const int b = bh >> 3, h = bh & 7;
  const int t = threadIdx.x;
  const size_t rowbase = (size_t)(b * 1024 + c * 64);
  {
    const int s = t >> 2, dg = t & 3;
#pragma unroll
    for (int ii = 0; ii < 4; ++ii) {
      const int d = dg * 16 + ii * 4;
      *(float4*)&ks[s * 68 + d] = *(const float4*)&kbuf[(rowbase + s) * 512 + h * 64 + d];
      *(float4*)&vs[s * 68 + d] = *(const float4*)&vbuf[(rowbase + s) * 512 + h * 64 + d];
    }
  }
  if (t < 64) zp[t] = zc[(size_t)(bh * 16 + c) * 64 + t];
  const int i = t & 63, mg = t >> 6;
  float q[64];
#pragma unroll
  for (int dd = 0; dd < 64; dd += 4) {
    float4 qq = *(const float4*)&qbuf[(rowbase + i) * 512 + h * 64 + dd];
    q[dd] = qq.x; q[dd + 1] = qq.y; q[dd + 2] = qq.z; q[dd + 3] = qq.w;
  }
  __syncthreads();
  float acc[16] = {};
  float den = 0.f;
  for (int j = 0; j < 64; ++j) {
    float s = 0.f;
#pragma unroll
    for (int dd = 0; dd < 64; dd += 4) {
      float4 kk = *(const float4*)&ks[j * 68 + dd];
      s += q[dd] * kk.x + q[dd + 1] * kk.y + q[dd + 2] * kk.z + q[dd + 3] * kk.w;
    }
    s = (j <= i) ? s : 0.f;                 // causal mask (inclusive)
    den += s;
#pragma unroll
    for (int mi = 0; mi < 16; mi += 4) {
      float4 vv = *(const float4*)&vs[j * 68 + mg * 16 + mi];
      acc[mi]     += s * vv.x; acc[mi + 1] += s * vv.y;
      acc[mi + 2] += s * vv.z; acc[mi + 3] += s * vv.w;
    }
  }
  __syncthreads();
  {                                          // reuse ks[] for KV prefix tile
    const float* kvp = KVc + (size_t)(bh * 16 + c) * 4096;
    const int dg2 = t >> 2, mg2 = t & 3;
#pragma unroll
    for (int ii = 0; ii < 4; ++ii) {
      const int mc = mg2 * 16 + ii * 4;
      *(float4*)&ks[dg2 * 68 + mc] = *(const float4*)&kvp[dg2 * 64 + mc];
    }
  }
  __syncthreads();
#pragma unroll
  for (int dd = 0; dd < 64; ++dd) {
    const float qd = q[dd];
    den += qd * zp[dd];
#pragma unroll
    for (int mi = 0; mi < 16; mi += 4) {
      float4 kv = *(const float4*)&ks[dd * 68 + mg * 16 + mi];
      acc[mi]     += qd * kv.x; acc[mi + 1] += qd * kv.y;
      acc[mi + 2] += qd * kv.z; acc[mi + 3] += qd * kv.w;
    }
  }
  const float rden = 1.f / (den + 1e-6f);
#pragma unroll
  for (int mi = 0; mi < 16; mi += 4)
    *(ushort4*)&out[(rowbase + i) * 512 + h * 64 + mg * 16 + mi] =
        make_ushort4(f2bf(acc[mi] * rden), f2bf(acc[mi + 1] * rden),
                     f2bf(acc[mi + 2] * rden), f2bf(acc[mi + 3] * rden));
}

// ---------------------------------------------------------------------------
// CA apply: KVtot = sum of 16 chunk partials; out = Q@KVtot / (q.ztot + eps)
// ---------------------------------------------------------------------------
__global__ __launch_bounds__(256) void ca_apply(
    const float* __restrict__ qbuf, const float* __restrict__ KVc,
    const float* __restrict__ zc, u16* __restrict__ out)
{
  __shared__ __align__(16) float kv[64 * 68];
  __shared__ float zt[64];
  const int c = blockIdx.x, bh = blockIdx.y;
  const int b = bh >> 3, h = bh & 7;
  const int t = threadIdx.x;
  {
    const int dg = t >> 2, mq = t & 3;
    float4 s0 = make_float4(0, 0, 0, 0), s1 = s0, s2 = s0, s3 = s0;
    const float* kvp = KVc + (size_t)bh * 16 * 4096 + dg * 64 + mq * 16;
    for (int cc = 0; cc < 16; ++cc) {
      const float* p = kvp + (size_t)cc * 4096;
      float4 a0 = *(const float4*)&p[0];
      float4 a1 = *(const float4*)&p[4];
      float4 a2 = *(const float4*)&p[8];
      float4 a3 = *(const float4*)&p[12];
      s0.x += a0.x; s0.y += a0.y; s0.z += a0.z; s0.w += a0.w;
      s1.x += a1.x; s1.y += a1.y; s1.z += a1.z; s1.w += a1.w;
      s2.x += a2.x; s2.y += a2.y; s2.z += a2.z; s2.w += a2.w;
      s3.x += a3.x; s3.y += a3.y; s3.z += a3.z; s3.w += a3.w;
    }
    *(float4*)&kv[dg * 68 + mq * 16 + 0]  = s0;
    *(float4*)&kv[dg * 68 + mq * 16 + 4]  = s1;
    *(float4*)&kv[dg * 68 + mq * 16 + 8]  = s2;
    *(float4*)&kv[dg * 68 + mq * 16 + 12] = s3;
  }
  if (t < 64) {
    float z = 0.f;
    for (int cc = 0; cc < 16; ++cc) z += zc[(size_t)bh * 16 * 64 + cc * 64 + t];
    zt[t] = z;
  }
  const int i = t & 63, mg = t >> 6;
  const size_t rowbase = (size_t)(b * 1024 + c * 64);
  float q[64];
#pragma unroll
  for (int dd = 0; dd < 64; dd += 4) {
    float4 qq = *(const float4*)&qbuf[(rowbase + i) * 512 + h * 64 + dd];
    q[dd] = qq.x; q[dd + 1] = qq.y; q[dd + 2] = qq.z; q[dd + 3] = qq.w;
  }
  __syncthreads();
  float acc[16] = {};
  float den = 0.f;
#pragma unroll
  for (int dd = 0; dd < 64; ++dd) {
    const float qd = q[dd];
    den += qd * zt[dd];
#pragma unroll
    for (int mi = 0; mi < 16; mi += 4) {
      float4 k4 = *(const float4*)&kv[dd * 68 + mg * 16 + mi];
      acc[mi]     += qd * k4.x; acc[mi + 1] += qd * k4.y;
      acc[mi + 2] += qd * k4.z; acc[mi + 3] += qd * k4.w;
    }
  }
  const float rden = 1.f / (den + 1e-6f);
#pragma unroll
  for (int mi = 0; mi < 16; mi += 4)
    *(ushort4*)&out[(rowbase + i) * 512 + h * 64 + mg * 16 + mi] =
        make_ushort4(f2bf(acc[mi] * rden), f2bf(acc[mi + 1] * rden),
                     f2bf(acc[mi + 2] * rden), f2bf(acc[mi + 3] * rden));
}

// ---------------------------------------------------------------------------
// LayerNorm: x = LN(x + a) in place (f32). 1 wave per 512-col row, 4 rows/block
// ---------------------------------------------------------------------------
__global__ __launch_bounds__(256) void ln_residual(
    float* __restrict__ x, const float* __restrict__ a,
    const float* __restrict__ g, const float* __restrict__ bt)
{
  const int t = threadIdx.x, lane = t & 63, w = t >> 6;
  const int row = blockIdx.x * 4 + w;
  float* xr = x + (size_t)row * 512;
  const float* ar = a + (size_t)row * 512;
  float4 x0 = *(const float4*)&xr[lane * 8];
  float4 x1 = *(const float4*)&xr[lane * 8 + 4];
  float4 a0 = *(const float4*)&ar[lane * 8];
  float4 a1 = *(const float4*)&ar[lane * 8 + 4];
  float v[8];
  v[0] = x0.x + a0.x; v[1] = x0.y + a0.y; v[2] = x0.z + a0.z; v[3] = x0.w + a0.w;
  v[4] = x1.x + a1.x; v[5] = x1.y + a1.y; v[6] = x1.z + a1.z; v[7] = x1.w + a1.w;
  float s = 0.f, sq = 0.f;
#pragma unroll
  for (int i = 0; i < 8; ++i) { s += v[i]; sq += v[i] * v[i]; }
#pragma unroll
  for (int off = 32; off > 0; off >>= 1) {
    s += __shfl_xor(s, off, 64);
    sq += __shfl_xor(sq, off, 64);
  }
  const float mean = s * (1.f / 512.f);
  const float var = sq * (1.f / 512.f) - mean * mean;
  const float rstd = rsqrtf(var + 1e-5f);
  float o[8];
#pragma unroll
  for (int i = 0; i < 8; ++i) {
    const int col = lane * 8 + i;
    o[i] = (v[i] - mean) * rstd * g[col] + bt[col];
  }
  *(float4*)&xr[lane * 8]     = make_float4(o[0], o[1], o[2], o[3]);
  *(float4*)&xr[lane * 8 + 4] = make_float4(o[4], o[5], o[6], o[7]);
}

__global__ __launch_bounds__(256) void ln_final(
    const float* __restrict__ x, const float* __restrict__ g,
    const float* __restrict__ bt, float* __restrict__ out)
{
  const int t = threadIdx.x, lane = t & 63, w = t >> 6;
  const int row = blockIdx.x * 4 + w;
  const float* xr = x + (size_t)row * 512;
  float4 x0 = *(const float4*)&xr[lane * 8];
  float4 x1 = *(const float4*)&xr[lane * 8 + 4];
  float v[8] = { x0.x, x0.y, x0.z, x0.w, x1.x, x1.y, x1.z, x1.w };
  float s = 0.f, sq = 0.f;
#pragma unroll
  for (int i = 0; i < 8; ++i) { s += v[i]; sq += v[i] * v[i]; }
#pragma unroll
  for (int off = 32; off > 0; off >>= 1) {
    s += __shfl_xor(s, off, 64);
    sq += __shfl_xor(sq, off, 64);
  }
  const float mean = s * (1.f / 512.f);
  const float var = sq * (1.f / 512.f) - mean * mean;
  const float rstd = rsqrtf(var + 1e-5f);
  float o[8];
#pragma unroll
  for (int i = 0; i < 8; ++i) {
    const int col = lane * 8 + i;
    o[i] = (v[i] - mean) * rstd * g[col] + bt[col];
  }
  *(float4*)&out[(size_t)row * 512 + lane * 8]     = make_float4(o[0], o[1], o[2], o[3]);
  *(float4*)&out[(size_t)row * 512 + lane * 8 + 4] = make_float4(o[4], o[5], o[6], o[7]);
}

// ---------------------------------------------------------------------------
extern "C" void kernel_launch(void* const* d_in, const int* in_sizes, int n_in,
                              void* d_out, int out_size, void* d_ws, size_t ws_size,
                              hipStream_t stream)
{
  (void)in_sizes; (void)n_in; (void)out_size; (void)ws_size;
  constexpr int Dm = 512, Lc = 4, FFc = 2048;

  const float* memory = (const float*)d_in[0];
  const float* target = (const float*)d_in[1];
  const float *saW[4], *sab[4], *caW[4], *cab[4];
  for (int j = 0; j < 4; ++j) {
    saW[j] = (const float*)d_in[2 + 2 * j];
    sab[j] = (const float*)d_in[3 + 2 * j];
    caW[j] = (const float*)d_in[10 + 2 * j];
    cab[j] = (const float*)d_in[11 + 2 * j];
  }
  const float* ffW1 = (const float*)d_in[18];
  const float* ffb1 = (const float*)d_in[19];
  const float* ffW2 = (const float*)d_in[20];
  const float* ffb2 = (const float*)d_in[21];
  const float* lng[4] = { (const float*)d_in[22], (const float*)d_in[24],
                          (const float*)d_in[26], (const float*)d_in[28] };
  const float* lnb[4] = { (const float*)d_in[23], (const float*)d_in[25],
                          (const float*)d_in[27], (const float*)d_in[29] };

  size_t off = 0;
  auto alloc = [&](size_t bytes) -> void* {
    void* p = (char*)d_ws + off;
    off += (bytes + 255) & ~(size_t)255;
    return p;
  };
  float* x    = (float*)alloc((size_t)2048 * 512 * 4);     //  4 MB
  float* qb   = (float*)alloc((size_t)2048 * 512 * 4);     //  4 MB
  float* kb   = (float*)alloc((size_t)2048 * 512 * 4);     //  4 MB
  float* vb   = (float*)alloc((size_t)2048 * 512 * 4);     //  4 MB
  u16*   attn = (u16*)alloc((size_t)2048 * 512 * 2);       //  2 MB
  u16*   ffh  = (u16*)alloc((size_t)2048 * 2048 * 2);      //  8 MB
  float* KVc  = (float*)alloc((size_t)16 * 16 * 4096 * 4); //  4 MB
  float* zcb  = (float*)alloc((size_t)16 * 16 * 64 * 4);   //  0.26 MB => ~30.3 MB

  hipMemcpyAsync(x, target, (size_t)2048 * 512 * 4, hipMemcpyDeviceToDevice, stream);

  for (int i = 0; i < Lc; ++i) {
    const size_t wo  = (size_t)i * Dm * Dm;
    const size_t wo1 = (size_t)i * Dm * FFc;
    const size_t wo2 = (size_t)i * FFc * Dm;
    // ---- causal linear self-attention ----
    gemm_kernel<64, 1, 0, 0><<<dim3(16, 8), 256, 0, stream>>>(x, saW[0] + wo, sab[0] + i * Dm, qb, 2048, 512, 512);
    gemm_kernel<64, 1, 0, 0><<<dim3(16, 8), 256, 0, stream>>>(x, saW[1] + wo, sab[1] + i * Dm, kb, 2048, 512, 512);
    gemm_kernel<64, 0, 0, 0><<<dim3(16, 8), 256, 0, stream>>>(x, saW[2] + wo, sab[2] + i * Dm, vb, 2048, 512, 512);
    lin_chunk_sums<<<dim3(16, 16), 256, 0, stream>>>(kb, vb, KVc, zcb);
    lin_scan_exclusive<<<dim3(16, 16), 256, 0, stream>>>(KVc, zcb);
    sa_apply<<<dim3(16, 16), 256, 0, stream>>>(qb, kb, vb, KVc, zcb, attn);
    gemm_kernel<64, 0, 1, 0><<<dim3(16, 8), 256, 0, stream>>>(attn, saW[3] + wo, sab[3] + i * Dm, qb, 2048, 512, 512);
    ln_residual<<<512, 256, 0, stream>>>(x, qb, lng[0] + i * Dm, lnb[0] + i * Dm);
    // ---- linear cross-attention over memory ----
    gemm_kernel<64, 1, 0, 0><<<dim3(16, 8), 256, 0, stream>>>(x,      caW[0] + wo, cab[0] + i * Dm, qb, 2048, 512, 512);
    gemm_kernel<64, 1, 0, 0><<<dim3(16, 8), 256, 0, stream>>>(memory, caW[1] + wo, cab[1] + i * Dm, kb, 2048, 512, 512);
    gemm_kernel<64, 0, 0, 0><<<dim3(16, 8), 256, 0, stream>>>(memory, caW[2] + wo, cab[2] + i * Dm, vb, 2048, 512, 512);
    lin_chunk_sums<<<dim3(16, 16), 256, 0, stream>>>(kb, vb, KVc, zcb);
    ca_apply<<<dim3(16, 16), 256, 0, stream>>>(qb, KVc, zcb, attn);
    gemm_kernel<64, 0, 1, 0><<<dim3(16, 8), 256, 0, stream>>>(attn, caW[3] + wo, cab[3] + i * Dm, qb, 2048, 512, 512);
    ln_residual<<<512, 256, 0, stream>>>(x, qb, lng[1] + i * Dm, lnb[1] + i * Dm);
    // ---- FFN ----
    gemm_kernel<128, 2, 0, 1><<<dim3(16, 16), 256, 0, stream>>>(x, ffW1 + wo1, ffb1 + i * FFc, ffh, 2048, 2048, 512);
    gemm_kernel<64, 0, 1, 0><<<dim3(16, 8), 256, 0, stream>>>(ffh, ffW2 + wo2, ffb2 + i * Dm, qb, 2048, 512, 2048);
    ln_residual<<<512, 256, 0, stream>>>(x, qb, lng[2] + i * Dm, lnb[2] + i * Dm);
  }
  ln_final<<<512, 256, 0, stream>>>(x, lng[3], lnb[3], (float*)d_out);
}

// Round 4
// 907.348 us; speedup vs baseline: 1.8892x; 1.8892x over previous
//
#include <hip/hip_runtime.h>
#include <hip/hip_bf16.h>
#include <math.h>

// ---------------------------------------------------------------------------
// LinearTransformerCausalDecoder on MI355X (gfx950)
// B=2, S=M=1024, D=512, H=8, HD=64, L=4, FF=2048
// d_in / d_out are FLOAT32. Weights pre-transposed to bf16 Wt[N][K] once.
// Residual stream x, q/k/v, attention math: f32. attn/ffh: bf16.
// Workspace ~62.5 MB.
// ---------------------------------------------------------------------------

typedef unsigned short u16;
typedef __bf16 bf16x8 __attribute__((ext_vector_type(8)));
typedef float f32x4v __attribute__((ext_vector_type(4)));

#define DEVI __device__ __forceinline__

DEVI float bf2f(u16 u) { return __uint_as_float(((unsigned)u) << 16); }
DEVI u16 f2bf(float f) {
  unsigned u = __float_as_uint(f);
  u += 0x7FFFu + ((u >> 16) & 1u);   // RNE
  return (u16)(u >> 16);
}

// ---------------------------------------------------------------------------
// Weight transpose+convert: in f32 [mat][K][N] -> out bf16 [mat][N][K]
// ---------------------------------------------------------------------------
__global__ __launch_bounds__(256) void transpose_f2b(
    const float* __restrict__ in, u16* __restrict__ out, int K, int N)
{
  __shared__ float tile[64 * 65];
  const size_t mat = (size_t)blockIdx.z * K * N;
  const int n0 = blockIdx.x * 64, k0 = blockIdx.y * 64;
  const int t = threadIdx.x;
#pragma unroll
  for (int p = 0; p < 16; ++p) {
    const int e = t + p * 256;
    const int lk = e >> 6, ln = e & 63;
    tile[lk * 65 + ln] = in[mat + (size_t)(k0 + lk) * N + n0 + ln];
  }
  __syncthreads();
#pragma unroll
  for (int p = 0; p < 16; ++p) {
    const int e = t + p * 256;
    const int ln = e >> 6, lk = e & 63;
    out[mat + (size_t)(n0 + ln) * K + k0 + lk] = f2bf(tile[lk * 65 + ln]);
  }
}

// ---------------------------------------------------------------------------
// Fused multi-segment GEMM: for segment s (= by>>lognyb):
//   C_s = act_s(A_s[M][K] @ Wt_s^T + b_s)     Wt bf16 [N][K]
// Tile 64x64, BK=64, 4 waves (2x2), wave tile 32x32. mfma_f32_16x16x32_bf16.
// ADT: 0 A=f32, 1 A=bf16.  CDT: 0 C=f32, 1 C=bf16.  acts: 2 bits/segment
// (0 none, 1 phi=elu+1, 2 gelu exact).
// ---------------------------------------------------------------------------
template<int ADT, int CDT>
__global__ __launch_bounds__(256) void gemm64(
    const void* __restrict__ A0, const void* __restrict__ A1, const void* __restrict__ A2,
    const u16* __restrict__ W0, const u16* __restrict__ W1, const u16* __restrict__ W2,
    const float* __restrict__ b0, const float* __restrict__ b1, const float* __restrict__ b2,
    void* __restrict__ C0, void* __restrict__ C1, void* __restrict__ C2,
    int acts, int N, int K, int lognyb)
{
  constexpr int LDT = 72;                     // 144B row stride: 16B-aligned, 2-way reads
  __shared__ __align__(16) u16 As[64 * LDT];
  __shared__ __align__(16) u16 Bs[64 * LDT];
  const int tid = threadIdx.x;
  const int by = blockIdx.y;
  const int seg = by >> lognyb;
  const int ny = by & ((1 << lognyb) - 1);
  const void* Av = seg == 0 ? A0 : (seg == 1 ? A1 : A2);
  const u16*  W  = seg == 0 ? W0 : (seg == 1 ? W1 : W2);
  const float* bias = seg == 0 ? b0 : (seg == 1 ? b1 : b2);
  void* Cv = seg == 0 ? C0 : (seg == 1 ? C1 : C2);
  const int act = (acts >> (2 * seg)) & 3;

  const int bm0 = blockIdx.x * 64, bn0 = ny * 64;
  const int lane = tid & 63, wid = tid >> 6;
  const int wr = wid >> 1, wc = wid & 1;
  const int l15 = lane & 15, lg = lane >> 4;
  const int srow = tid >> 2, scg = (tid & 3) * 16;   // staging map
  f32x4v acc[2][2] = {};

  for (int k0 = 0; k0 < K; k0 += 64) {
    if (ADT == 0) {
      const float* A = (const float*)Av;
      const float* ap = &A[(size_t)(bm0 + srow) * K + k0 + scg];
#pragma unroll
      for (int i = 0; i < 4; ++i) {
        const float4 v = *(const float4*)&ap[i * 4];
        *(ushort4*)&As[srow * LDT + scg + i * 4] =
            make_ushort4(f2bf(v.x), f2bf(v.y), f2bf(v.z), f2bf(v.w));
      }
    } else {
      const u16* A = (const u16*)Av;
#pragma unroll
      for (int i = 0; i < 2; ++i)
        *(uint4*)&As[srow * LDT + scg + i * 8] =
            *(const uint4*)&A[(size_t)(bm0 + srow) * K + k0 + scg + i * 8];
    }
#pragma unroll
    for (int i = 0; i < 2; ++i)
      *(uint4*)&Bs[srow * LDT + scg + i * 8] =
          *(const uint4*)&W[(size_t)(bn0 + srow) * K + k0 + scg + i * 8];
    __syncthreads();
    bf16x8 af[2][2], bw[2][2];
#pragma unroll
    for (int kk = 0; kk < 2; ++kk) {
#pragma unroll
      for (int mm = 0; mm < 2; ++mm)
        af[kk][mm] = *(const bf16x8*)&As[(wr * 32 + mm * 16 + l15) * LDT + kk * 32 + lg * 8];
#pragma unroll
      for (int nn = 0; nn < 2; ++nn)
        bw[kk][nn] = *(const bf16x8*)&Bs[(wc * 32 + nn * 16 + l15) * LDT + kk * 32 + lg * 8];
    }
#pragma unroll
    for (int kk = 0; kk < 2; ++kk)
#pragma unroll
      for (int mm = 0; mm < 2; ++mm)
#pragma unroll
        for (int nn = 0; nn < 2; ++nn)
          acc[mm][nn] = __builtin_amdgcn_mfma_f32_16x16x32_bf16(af[kk][mm], bw[kk][nn], acc[mm][nn], 0, 0, 0);
    __syncthreads();
  }
  // epilogue: D mapping col=lane&15, row=(lane>>4)*4+r
#pragma unroll
  for (int nn = 0; nn < 2; ++nn) {
    const int col = bn0 + wc * 32 + nn * 16 + l15;
    const float bv = bias[col];
#pragma unroll
    for (int mm = 0; mm < 2; ++mm) {
#pragma unroll
      for (int r = 0; r < 4; ++r) {
        const int row = bm0 + wr * 32 + mm * 16 + lg * 4 + r;
        float v = acc[mm][nn][r] + bv;
        if (act == 1) v = v > 0.f ? v + 1.f : __expf(v);
        else if (act == 2) v = 0.5f * v * (1.f + erff(v * 0.70710678f));
        if (CDT == 0) ((float*)Cv)[(size_t)row * N + col] = v;
        else          ((u16*)Cv)[(size_t)row * N + col] = f2bf(v);
      }
    }
  }
}

// ---------------------------------------------------------------------------
// Linear attention chunk sums: per (chunk c, b, h):
//   KVc[bh][c][d][m] = sum_{s in chunk} k[s][d]*v[s][m],  zc = sum k
// ---------------------------------------------------------------------------
__global__ __launch_bounds__(256) void lin_chunk_sums(
    const float* __restrict__ kbuf, const float* __restrict__ vbuf,
    float* __restrict__ KVc, float* __restrict__ zc)
{
  __shared__ __align__(16) float ks[64 * 68];
  __shared__ __align__(16) float vs[64 * 68];
  const int c = blockIdx.x, bh = blockIdx.y;
  const int b = bh >> 3, h = bh & 7;
  const int t = threadIdx.x;
  const size_t rowbase = (size_t)(b * 1024 + c * 64);
  {
    const int s = t >> 2, dg = t & 3;
#pragma unroll
    for (int ii = 0; ii < 4; ++ii) {
      const int d = dg * 16 + ii * 4;
      *(float4*)&ks[s * 68 + d] = *(const float4*)&kbuf[(rowbase + s) * 512 + h * 64 + d];
      *(float4*)&vs[s * 68 + d] = *(const float4*)&vbuf[(rowbase + s) * 512 + h * 64 + d];
    }
  }
  __syncthreads();
  const int m = t & 63, ig = t >> 6;
  float acc[16] = {};
  for (int ss = 0; ss < 64; ++ss) {
    const float vv = vs[ss * 68 + m];
#pragma unroll
    for (int i = 0; i < 16; i += 4) {
      float4 kk = *(const float4*)&ks[ss * 68 + ig * 16 + i];
      acc[i]     += kk.x * vv; acc[i + 1] += kk.y * vv;
      acc[i + 2] += kk.z * vv; acc[i + 3] += kk.w * vv;
    }
  }
  float* kvout = KVc + (size_t)(bh * 16 + c) * 4096;
#pragma unroll
  for (int i = 0; i < 16; ++i) kvout[(ig * 16 + i) * 64 + m] = acc[i];
  if (t < 64) {
    float z = 0.f;
    for (int ss = 0; ss < 64; ++ss) z += ks[ss * 68 + t];
    zc[(size_t)(bh * 16 + c) * 64 + t] = z;
  }
}

// exclusive prefix over the 16 chunks, per cell.  grid (grp=16, bh=16)
__global__ __launch_bounds__(256) void lin_scan_exclusive(
    float* __restrict__ KVc, float* __restrict__ zc)
{
  const int grp = blockIdx.x, bh = blockIdx.y, t = threadIdx.x;
  const size_t base = (size_t)bh * 16 * 4096 + grp * 256 + t;
  float run = 0.f;
#pragma unroll
  for (int c = 0; c < 16; ++c) {
    const float tmp = KVc[base + (size_t)c * 4096];
    KVc[base + (size_t)c * 4096] = run;
    run += tmp;
  }
  if (grp == 0 && t < 64) {
    const size_t zb = (size_t)bh * 16 * 64 + t;
    float rz = 0.f;
#pragma unroll
    for (int c = 0; c < 16; ++c) {
      const float tmp = zc[zb + c * 64];
      zc[zb + c * 64] = rz;
      rz += tmp;
    }
  }
}

// ---------------------------------------------------------------------------
// SA apply: out = (intra-chunk masked QK^T V + Q @ KV_prefix) / (den + eps)
// out bf16.  grid (c=16, bh=16); row i = t&63, m-group mg = t>>6.
// ---------------------------------------------------------------------------
__global__ __launch_bounds__(256) void sa_apply(
    const float* __restrict__ qbuf, const float* __restrict__ kbuf,
    const float* __restrict__ vbuf, const float* __restrict__ KVc,
    const float* __restrict__ zc, u16* __restrict__ out)
{
  __shared__ __align__(16) float ks[64 * 68];
  __shared__ __align__(16) float vs[64 * 68];
  __shared__ float zp[64];
  const int c = blockIdx.x, bh = blockIdx.y;
  const int b = bh >> 3, h = bh & 7;
  const int t = threadIdx.x;
  const size_t rowbase = (size_t)(b * 1024 + c * 64);
  {
    const int s = t >> 2, dg = t & 3;
#pragma unroll
    for (int ii = 0; ii < 4; ++ii) {
      const int d = dg * 16 + ii * 4;
      *(float4*)&ks[s * 68 + d] = *(const float4*)&kbuf[(rowbase + s) * 512 + h * 64 + d];
      *(float4*)&vs[s * 68 + d] = *(const float4*)&vbuf[(rowbase + s) * 512 + h * 64 + d];
    }
  }
  if (t < 64) zp[t] = zc[(size_t)(bh * 16 + c) * 64 + t];
  const int i = t & 63, mg = t >> 6;
  float q[64];
#pragma unroll
  for (int dd = 0; dd < 64; dd += 4) {
    float4 qq = *(const float4*)&qbuf[(rowbase + i) * 512 + h * 64 + dd];
    q[dd] = qq.x; q[dd + 1] = qq.y; q[dd + 2] = qq.z; q[dd + 3] = qq.w;
  }
  __syncthreads();
  float acc[16] = {};
  float den = 0.f;
  for (int j = 0; j < 64; ++j) {
    float s = 0.f;
#pragma unroll
    for (int dd = 0; dd < 64; dd += 4) {
      float4 kk = *(const float4*)&ks[j * 68 + dd];
      s += q[dd] * kk.x + q[dd + 1] * kk.y + q[dd + 2] * kk.z + q[dd + 3] * kk.w;
    }
    s = (j <= i) ? s : 0.f;                 // causal mask (inclusive)
    den += s;
#pragma unroll
    for (int mi = 0; mi < 16; mi += 4) {
      float4 vv = *(const float4*)&vs[j * 68 + mg * 16 + mi];
      acc[mi]     += s * vv.x; acc[mi + 1] += s * vv.y;
      acc[mi + 2] += s * vv.z; acc[mi + 3] += s * vv.w;
    }
  }
  __syncthreads();
  {                                          // reuse ks[] for KV prefix tile
    const float* kvp = KVc + (size_t)(bh * 16 + c) * 4096;
    const int dg2 = t >> 2, mg2 = t & 3;
#pragma unroll
    for (int ii = 0; ii < 4; ++ii) {
      const int mc = mg2 * 16 + ii * 4;
      *(float4*)&ks[dg2 * 68 + mc] = *(const float4*)&kvp[dg2 * 64 + mc];
    }
  }
  __syncthreads();
#pragma unroll
  for (int dd = 0; dd < 64; ++dd) {
    const float qd = q[dd];
    den += qd * zp[dd];
#pragma unroll
    for (int mi = 0; mi < 16; mi += 4) {
      float4 kv = *(const float4*)&ks[dd * 68 + mg * 16 + mi];
      acc[mi]     += qd * kv.x; acc[mi + 1] += qd * kv.y;
      acc[mi + 2] += qd * kv.z; acc[mi + 3] += qd * kv.w;
    }
  }
  const float rden = 1.f / (den + 1e-6f);
#pragma unroll
  for (int mi = 0; mi < 16; mi += 4)
    *(ushort4*)&out[(rowbase + i) * 512 + h * 64 + mg * 16 + mi] =
        make_ushort4(f2bf(acc[mi] * rden), f2bf(acc[mi + 1] * rden),
                     f2bf(acc[mi + 2] * rden), f2bf(acc[mi + 3] * rden));
}

// ---------------------------------------------------------------------------
// CA apply: KVtot = sum of 16 chunk partials; out = Q@KVtot / (q.ztot + eps)
// ---------------------------------------------------------------------------
__global__ __launch_bounds__(256) void ca_apply(
    const float* __restrict__ qbuf, const float* __restrict__ KVc,
    const float* __restrict__ zc, u16* __restrict__ out)
{
  __shared__ __align__(16) float kv[64 * 68];
  __shared__ float zt[64];
  const int c = blockIdx.x, bh = blockIdx.y;
  const int b = bh >> 3, h = bh & 7;
  const int t = threadIdx.x;
  {
    const int dg = t >> 2, mq = t & 3;
    float4 s0 = make_float4(0, 0, 0, 0), s1 = s0, s2 = s0, s3 = s0;
    const float* kvp = KVc + (size_t)bh * 16 * 4096 + dg * 64 + mq * 16;
    for (int cc = 0; cc < 16; ++cc) {
      const float* p = kvp + (size_t)cc * 4096;
      float4 a0 = *(const float4*)&p[0];
      float4 a1 = *(const float4*)&p[4];
      float4 a2 = *(const float4*)&p[8];
      float4 a3 = *(const float4*)&p[12];
      s0.x += a0.x; s0.y += a0.y; s0.z += a0.z; s0.w += a0.w;
      s1.x += a1.x; s1.y += a1.y; s1.z += a1.z; s1.w += a1.w;
      s2.x += a2.x; s2.y += a2.y; s2.z += a2.z; s2.w += a2.w;
      s3.x += a3.x; s3.y += a3.y; s3.z += a3.z; s3.w += a3.w;
    }
    *(float4*)&kv[dg * 68 + mq * 16 + 0]  = s0;
    *(float4*)&kv[dg * 68 + mq * 16 + 4]  = s1;
    *(float4*)&kv[dg * 68 + mq * 16 + 8]  = s2;
    *(float4*)&kv[dg * 68 + mq * 16 + 12] = s3;
  }
  if (t < 64) {
    float z = 0.f;
    for (int cc = 0; cc < 16; ++cc) z += zc[(size_t)bh * 16 * 64 + cc * 64 + t];
    zt[t] = z;
  }
  const int i = t & 63, mg = t >> 6;
  const size_t rowbase = (size_t)(b * 1024 + c * 64);
  float q[64];
#pragma unroll
  for (int dd = 0; dd < 64; dd += 4) {
    float4 qq = *(const float4*)&qbuf[(rowbase + i) * 512 + h * 64 + dd];
    q[dd] = qq.x; q[dd + 1] = qq.y; q[dd + 2] = qq.z; q[dd + 3] = qq.w;
  }
  __syncthreads();
  float acc[16] = {};
  float den = 0.f;
#pragma unroll
  for (int dd = 0; dd < 64; ++dd) {
    const float qd = q[dd];
    den += qd * zt[dd];
#pragma unroll
    for (int mi = 0; mi < 16; mi += 4) {
      float4 k4 = *(const float4*)&kv[dd * 68 + mg * 16 + mi];
      acc[mi]     += qd * k4.x; acc[mi + 1] += qd * k4.y;
      acc[mi + 2] += qd * k4.z; acc[mi + 3] += qd * k4.w;
    }
  }
  const float rden = 1.f / (den + 1e-6f);
#pragma unroll
  for (int mi = 0; mi < 16; mi += 4)
    *(ushort4*)&out[(rowbase + i) * 512 + h * 64 + mg * 16 + mi] =
        make_ushort4(f2bf(acc[mi] * rden), f2bf(acc[mi + 1] * rden),
                     f2bf(acc[mi + 2] * rden), f2bf(acc[mi + 3] * rden));
}

// ---------------------------------------------------------------------------
// LayerNorm: x = LN(x + a) in place (f32). 1 wave per 512-col row, 4 rows/block
// ---------------------------------------------------------------------------
__global__ __launch_bounds__(256) void ln_residual(
    float* __restrict__ x, const float* __restrict__ a,
    const float* __restrict__ g, const float* __restrict__ bt)
{
  const int t = threadIdx.x, lane = t & 63, w = t >> 6;
  const int row = blockIdx.x * 4 + w;
  float* xr = x + (size_t)row * 512;
  const float* ar = a + (size_t)row * 512;
  float4 x0 = *(const float4*)&xr[lane * 8];
  float4 x1 = *(const float4*)&xr[lane * 8 + 4];
  float4 a0 = *(const float4*)&ar[lane * 8];
  float4 a1 = *(const float4*)&ar[lane * 8 + 4];
  float v[8];
  v[0] = x0.x + a0.x; v[1] = x0.y + a0.y; v[2] = x0.z + a0.z; v[3] = x0.w + a0.w;
  v[4] = x1.x + a1.x; v[5] = x1.y + a1.y; v[6] = x1.z + a1.z; v[7] = x1.w + a1.w;
  float s = 0.f, sq = 0.f;
#pragma unroll
  for (int i = 0; i < 8; ++i) { s += v[i]; sq += v[i] * v[i]; }
#pragma unroll
  for (int off = 32; off > 0; off >>= 1) {
    s += __shfl_xor(s, off, 64);
    sq += __shfl_xor(sq, off, 64);
  }
  const float mean = s * (1.f / 512.f);
  const float var = sq * (1.f / 512.f) - mean * mean;
  const float rstd = rsqrtf(var + 1e-5f);
  float o[8];
#pragma unroll
  for (int i = 0; i < 8; ++i) {
    const int col = lane * 8 + i;
    o[i] = (v[i] - mean) * rstd * g[col] + bt[col];
  }
  *(float4*)&xr[lane * 8]     = make_float4(o[0], o[1], o[2], o[3]);
  *(float4*)&xr[lane * 8 + 4] = make_float4(o[4], o[5], o[6], o[7]);
}

__global__ __launch_bounds__(256) void ln_final(
    const float* __restrict__ x, const float* __restrict__ g,
    const float* __restrict__ bt, float* __restrict__ out)
{
  const int t = threadIdx.x, lane = t & 63, w = t >> 6;
  const int row = blockIdx.x * 4 + w;
  const float* xr = x + (size_t)row * 512;
  float4 x0 = *(const float4*)&xr[lane * 8];
  float4 x1 = *(const float4*)&xr[lane * 8 + 4];
  float v[8] = { x0.x, x0.y, x0.z, x0.w, x1.x, x1.y, x1.z, x1.w };
  float s = 0.f, sq = 0.f;
#pragma unroll
  for (int i = 0; i < 8; ++i) { s += v[i]; sq += v[i] * v[i]; }
#pragma unroll
  for (int off = 32; off > 0; off >>= 1) {
    s += __shfl_xor(s, off, 64);
    sq += __shfl_xor(sq, off, 64);
  }
  const float mean = s * (1.f / 512.f);
  const float var = sq * (1.f / 512.f) - mean * mean;
  const float rstd = rsqrtf(var + 1e-5f);
  float o[8];
#pragma unroll
  for (int i = 0; i < 8; ++i) {
    const int col = lane * 8 + i;
    o[i] = (v[i] - mean) * rstd * g[col] + bt[col];
  }
  *(float4*)&out[(size_t)row * 512 + lane * 8]     = make_float4(o[0], o[1], o[2], o[3]);
  *(float4*)&out[(size_t)row * 512 + lane * 8 + 4] = make_float4(o[4], o[5], o[6], o[7]);
}

// ---------------------------------------------------------------------------
extern "C" void kernel_launch(void* const* d_in, const int* in_sizes, int n_in,
                              void* d_out, int out_size, void* d_ws, size_t ws_size,
                              hipStream_t stream)
{
  (void)in_sizes; (void)n_in; (void)out_size; (void)ws_size;
  constexpr int Dm = 512, Lc = 4, FFc = 2048;

  const float* memory = (const float*)d_in[0];
  const float* target = (const float*)d_in[1];
  const float *saW[4], *sab[4], *caW[4], *cab[4];
  for (int j = 0; j < 4; ++j) {
    saW[j] = (const float*)d_in[2 + 2 * j];
    sab[j] = (const float*)d_in[3 + 2 * j];
    caW[j] = (const float*)d_in[10 + 2 * j];
    cab[j] = (const float*)d_in[11 + 2 * j];
  }
  const float* ffW1 = (const float*)d_in[18];
  const float* ffb1 = (const float*)d_in[19];
  const float* ffW2 = (const float*)d_in[20];
  const float* ffb2 = (const float*)d_in[21];
  const float* lng[4] = { (const float*)d_in[22], (const float*)d_in[24],
                          (const float*)d_in[26], (const float*)d_in[28] };
  const float* lnb[4] = { (const float*)d_in[23], (const float*)d_in[25],
                          (const float*)d_in[27], (const float*)d_in[29] };

  size_t off = 0;
  auto alloc = [&](size_t bytes) -> void* {
    void* p = (char*)d_ws + off;
    off += (bytes + 255) & ~(size_t)255;
    return p;
  };
  u16* WtS[4]; u16* WtC[4];
  for (int j = 0; j < 4; ++j) WtS[j] = (u16*)alloc((size_t)Lc * Dm * Dm * 2);   // 8 MB
  for (int j = 0; j < 4; ++j) WtC[j] = (u16*)alloc((size_t)Lc * Dm * Dm * 2);   // 8 MB
  u16* WtF1 = (u16*)alloc((size_t)Lc * Dm * FFc * 2);                           // 8 MB
  u16* WtF2 = (u16*)alloc((size_t)Lc * FFc * Dm * 2);                           // 8 MB
  float* x    = (float*)alloc((size_t)2048 * 512 * 4);     //  4 MB
  float* qb   = (float*)alloc((size_t)2048 * 512 * 4);     //  4 MB
  float* kb   = (float*)alloc((size_t)2048 * 512 * 4);     //  4 MB
  float* vb   = (float*)alloc((size_t)2048 * 512 * 4);     //  4 MB
  u16*   attn = (u16*)alloc((size_t)2048 * 512 * 2);       //  2 MB
  u16*   ffh  = (u16*)alloc((size_t)2048 * 2048 * 2);      //  8 MB
  float* KVc  = (float*)alloc((size_t)16 * 16 * 4096 * 4); //  4 MB
  float* zcb  = (float*)alloc((size_t)16 * 16 * 64 * 4);   //  0.26 MB => ~62.5 MB

  // one-time weight transposes f32 [K][N] -> bf16 [N][K]
  for (int j = 0; j < 4; ++j) {
    transpose_f2b<<<dim3(8, 8, 4), 256, 0, stream>>>(saW[j], WtS[j], Dm, Dm);
    transpose_f2b<<<dim3(8, 8, 4), 256, 0, stream>>>(caW[j], WtC[j], Dm, Dm);
  }
  transpose_f2b<<<dim3(32, 8, 4), 256, 0, stream>>>(ffW1, WtF1, Dm, FFc);
  transpose_f2b<<<dim3(8, 32, 4), 256, 0, stream>>>(ffW2, WtF2, FFc, Dm);

  hipMemcpyAsync(x, target, (size_t)2048 * 512 * 4, hipMemcpyDeviceToDevice, stream);

  for (int i = 0; i < Lc; ++i) {
    const size_t wo  = (size_t)i * Dm * Dm;
    const size_t wo1 = (size_t)i * Dm * FFc;
    const size_t wo2 = (size_t)i * FFc * Dm;
    // ---- causal linear self-attention: fused QKV ----
    gemm64<0, 0><<<dim3(32, 24), 256, 0, stream>>>(
        x, x, x, WtS[0] + wo, WtS[1] + wo, WtS[2] + wo,
        sab[0] + i * Dm, sab[1] + i * Dm, sab[2] + i * Dm,
        qb, kb, vb, 0x05 /*phi,phi,none*/, 512, 512, 3);
    lin_chunk_sums<<<dim3(16, 16), 256, 0, stream>>>(kb, vb, KVc, zcb);
    lin_scan_exclusive<<<dim3(16, 16), 256, 0, stream>>>(KVc, zcb);
    sa_apply<<<dim3(16, 16), 256, 0, stream>>>(qb, kb, vb, KVc, zcb, attn);
    gemm64<1, 0><<<dim3(32, 8), 256, 0, stream>>>(
        attn, attn, attn, WtS[3] + wo, WtS[3] + wo, WtS[3] + wo,
        sab[3] + i * Dm, sab[3] + i * Dm, sab[3] + i * Dm,
        qb, qb, qb, 0, 512, 512, 3);
    ln_residual<<<512, 256, 0, stream>>>(x, qb, lng[0] + i * Dm, lnb[0] + i * Dm);
    // ---- linear cross-attention: fused Q(x), K(mem), V(mem) ----
    gemm64<0, 0><<<dim3(32, 24), 256, 0, stream>>>(
        x, memory, memory, WtC[0] + wo, WtC[1] + wo, WtC[2] + wo,
        cab[0] + i * Dm, cab[1] + i * Dm, cab[2] + i * Dm,
        qb, kb, vb, 0x05, 512, 512, 3);
    lin_chunk_sums<<<dim3(16, 16), 256, 0, stream>>>(kb, vb, KVc, zcb);
    ca_apply<<<dim3(16, 16), 256, 0, stream>>>(qb, KVc, zcb, attn);
    gemm64<1, 0><<<dim3(32, 8), 256, 0, stream>>>(
        attn, attn, attn, WtC[3] + wo, WtC[3] + wo, WtC[3] + wo,
        cab[3] + i * Dm, cab[3] + i * Dm, cab[3] + i * Dm,
        qb, qb, qb, 0, 512, 512, 3);
    ln_residual<<<512, 256, 0, stream>>>(x, qb, lng[1] + i * Dm, lnb[1] + i * Dm);
    // ---- FFN ----
    gemm64<0, 1><<<dim3(32, 32), 256, 0, stream>>>(
        x, x, x, WtF1 + wo1, WtF1 + wo1, WtF1 + wo1,
        ffb1 + i * FFc, ffb1 + i * FFc, ffb1 + i * FFc,
        ffh, ffh, ffh, 2 /*gelu*/, 2048, 512, 5);
    gemm64<1, 0><<<dim3(32, 8), 256, 0, stream>>>(
        ffh, ffh, ffh, WtF2 + wo2, WtF2 + wo2, WtF2 + wo2,
        ffb2 + i * Dm, ffb2 + i * Dm, ffb2 + i * Dm,
        qb, qb, qb, 0, 512, 2048, 3);
    ln_residual<<<512, 256, 0, stream>>>(x, qb, lng[2] + i * Dm, lnb[2] + i * Dm);
  }
  ln_final<<<512, 256, 0, stream>>>(x, lng[3], lnb[3], (float*)d_out);
}

// Round 5
// 682.129 us; speedup vs baseline: 2.5130x; 1.3302x over previous
//
#include <hip/hip_runtime.h>
#include <hip/hip_bf16.h>
#include <math.h>

// ---------------------------------------------------------------------------
// LinearTransformerCausalDecoder on MI355X (gfx950)
// B=2, S=M=1024, D=512, H=8, HD=64, L=4, FF=2048
// d_in / d_out are FLOAT32. Weights pre-transposed to bf16 Wt[N][K] once.
// Attention tier now MFMA-based (64x64x64 per (chunk,head) unit).
// ---------------------------------------------------------------------------

typedef unsigned short u16;
typedef __bf16 bf16x8 __attribute__((ext_vector_type(8)));
typedef float f32x4v __attribute__((ext_vector_type(4)));

#define DEVI __device__ __forceinline__

DEVI float bf2f(u16 u) { return __uint_as_float(((unsigned)u) << 16); }
DEVI u16 f2bf(float f) {
  unsigned u = __float_as_uint(f);
  u += 0x7FFFu + ((u >> 16) & 1u);   // RNE
  return (u16)(u >> 16);
}

// ---------------------------------------------------------------------------
// Weight transpose+convert: in f32 [mat][K][N] -> out bf16 [mat][N][K]
// ---------------------------------------------------------------------------
__global__ __launch_bounds__(256) void transpose_f2b(
    const float* __restrict__ in, u16* __restrict__ out, int K, int N)
{
  __shared__ float tile[64 * 65];
  const size_t mat = (size_t)blockIdx.z * K * N;
  const int n0 = blockIdx.x * 64, k0 = blockIdx.y * 64;
  const int t = threadIdx.x;
#pragma unroll
  for (int p = 0; p < 16; ++p) {
    const int e = t + p * 256;
    const int lk = e >> 6, ln = e & 63;
    tile[lk * 65 + ln] = in[mat + (size_t)(k0 + lk) * N + n0 + ln];
  }
  __syncthreads();
#pragma unroll
  for (int p = 0; p < 16; ++p) {
    const int e = t + p * 256;
    const int ln = e >> 6, lk = e & 63;
    out[mat + (size_t)(n0 + ln) * K + k0 + lk] = f2bf(tile[lk * 65 + ln]);
  }
}

// ---------------------------------------------------------------------------
// Fused multi-segment GEMM: for segment s (= by>>lognyb):
//   C_s = act_s(A_s[M][K] @ Wt_s^T + b_s)     Wt bf16 [N][K]
// Tile 64x64, BK=64, 4 waves (2x2). ADT: 0 A=f32, 1 A=bf16. CDT likewise for C.
// acts: 2 bits/segment (0 none, 1 phi=elu+1, 2 gelu exact).
// ---------------------------------------------------------------------------
template<int ADT, int CDT>
__global__ __launch_bounds__(256) void gemm64(
    const void* __restrict__ A0, const void* __restrict__ A1, const void* __restrict__ A2,
    const u16* __restrict__ W0, const u16* __restrict__ W1, const u16* __restrict__ W2,
    const float* __restrict__ b0, const float* __restrict__ b1, const float* __restrict__ b2,
    void* __restrict__ C0, void* __restrict__ C1, void* __restrict__ C2,
    int acts, int N, int K, int lognyb)
{
  constexpr int LDT = 72;
  __shared__ __align__(16) u16 As[64 * LDT];
  __shared__ __align__(16) u16 Bs[64 * LDT];
  const int tid = threadIdx.x;
  const int by = blockIdx.y;
  const int seg = by >> lognyb;
  const int ny = by & ((1 << lognyb) - 1);
  const void* Av = seg == 0 ? A0 : (seg == 1 ? A1 : A2);
  const u16*  W  = seg == 0 ? W0 : (seg == 1 ? W1 : W2);
  const float* bias = seg == 0 ? b0 : (seg == 1 ? b1 : b2);
  void* Cv = seg == 0 ? C0 : (seg == 1 ? C1 : C2);
  const int act = (acts >> (2 * seg)) & 3;

  const int bm0 = blockIdx.x * 64, bn0 = ny * 64;
  const int lane = tid & 63, wid = tid >> 6;
  const int wr = wid >> 1, wc = wid & 1;
  const int l15 = lane & 15, lg = lane >> 4;
  const int srow = tid >> 2, scg = (tid & 3) * 16;
  f32x4v acc[2][2] = {};

  for (int k0 = 0; k0 < K; k0 += 64) {
    if (ADT == 0) {
      const float* A = (const float*)Av;
      const float* ap = &A[(size_t)(bm0 + srow) * K + k0 + scg];
#pragma unroll
      for (int i = 0; i < 4; ++i) {
        const float4 v = *(const float4*)&ap[i * 4];
        *(ushort4*)&As[srow * LDT + scg + i * 4] =
            make_ushort4(f2bf(v.x), f2bf(v.y), f2bf(v.z), f2bf(v.w));
      }
    } else {
      const u16* A = (const u16*)Av;
#pragma unroll
      for (int i = 0; i < 2; ++i)
        *(uint4*)&As[srow * LDT + scg + i * 8] =
            *(const uint4*)&A[(size_t)(bm0 + srow) * K + k0 + scg + i * 8];
    }
#pragma unroll
    for (int i = 0; i < 2; ++i)
      *(uint4*)&Bs[srow * LDT + scg + i * 8] =
          *(const uint4*)&W[(size_t)(bn0 + srow) * K + k0 + scg + i * 8];
    __syncthreads();
    bf16x8 af[2][2], bw[2][2];
#pragma unroll
    for (int kk = 0; kk < 2; ++kk) {
#pragma unroll
      for (int mm = 0; mm < 2; ++mm)
        af[kk][mm] = *(const bf16x8*)&As[(wr * 32 + mm * 16 + l15) * LDT + kk * 32 + lg * 8];
#pragma unroll
      for (int nn = 0; nn < 2; ++nn)
        bw[kk][nn] = *(const bf16x8*)&Bs[(wc * 32 + nn * 16 + l15) * LDT + kk * 32 + lg * 8];
    }
#pragma unroll
    for (int kk = 0; kk < 2; ++kk)
#pragma unroll
      for (int mm = 0; mm < 2; ++mm)
#pragma unroll
        for (int nn = 0; nn < 2; ++nn)
          acc[mm][nn] = __builtin_amdgcn_mfma_f32_16x16x32_bf16(af[kk][mm], bw[kk][nn], acc[mm][nn], 0, 0, 0);
    __syncthreads();
  }
#pragma unroll
  for (int nn = 0; nn < 2; ++nn) {
    const int col = bn0 + wc * 32 + nn * 16 + l15;
    const float bv = bias[col];
#pragma unroll
    for (int mm = 0; mm < 2; ++mm) {
#pragma unroll
      for (int r = 0; r < 4; ++r) {
        const int row = bm0 + wr * 32 + mm * 16 + lg * 4 + r;
        float v = acc[mm][nn][r] + bv;
        if (act == 1) v = v > 0.f ? v + 1.f : __expf(v);
        else if (act == 2) v = 0.5f * v * (1.f + erff(v * 0.70710678f));
        if (CDT == 0) ((float*)Cv)[(size_t)row * N + col] = v;
        else          ((u16*)Cv)[(size_t)row * N + col] = f2bf(v);
      }
    }
  }
}

// ---------------------------------------------------------------------------
// Chunk sums (MFMA): per (c,bh):  KVt[m][d] = sum_s V[s][m]*K[s][d] (f32 out),
// z[d] = sum_s K[s][d].  GEMM M=m,N=d,Kdim=s with A=V^T, B=K^T.
// ---------------------------------------------------------------------------
__global__ __launch_bounds__(256) void lin_chunk_mfma(
    const float* __restrict__ kbuf, const float* __restrict__ vbuf,
    float* __restrict__ KVc, float* __restrict__ zc)
{
  constexpr int LDT = 72;
  __shared__ __align__(16) u16 Kt[64 * LDT];   // Kt[d][s]
  __shared__ __align__(16) u16 Vt[64 * LDT];   // Vt[m][s]
  const int c = blockIdx.x, bh = blockIdx.y;
  const int b = bh >> 3, h = bh & 7;
  const int t = threadIdx.x;
  const size_t rowbase = (size_t)(b * 1024 + c * 64);
  const int sp = t >> 4, colq = (t & 15) * 4;
#pragma unroll
  for (int pp = 0; pp < 2; ++pp) {
    const int s0 = pp * 32 + 2 * sp;
    const float4 ka = *(const float4*)&kbuf[(rowbase + s0) * 512 + h * 64 + colq];
    const float4 kb_ = *(const float4*)&kbuf[(rowbase + s0 + 1) * 512 + h * 64 + colq];
    const float4 va = *(const float4*)&vbuf[(rowbase + s0) * 512 + h * 64 + colq];
    const float4 vb_ = *(const float4*)&vbuf[(rowbase + s0 + 1) * 512 + h * 64 + colq];
    *(unsigned*)&Kt[(colq + 0) * LDT + s0] = (unsigned)f2bf(ka.x) | ((unsigned)f2bf(kb_.x) << 16);
    *(unsigned*)&Kt[(colq + 1) * LDT + s0] = (unsigned)f2bf(ka.y) | ((unsigned)f2bf(kb_.y) << 16);
    *(unsigned*)&Kt[(colq + 2) * LDT + s0] = (unsigned)f2bf(ka.z) | ((unsigned)f2bf(kb_.z) << 16);
    *(unsigned*)&Kt[(colq + 3) * LDT + s0] = (unsigned)f2bf(ka.w) | ((unsigned)f2bf(kb_.w) << 16);
    *(unsigned*)&Vt[(colq + 0) * LDT + s0] = (unsigned)f2bf(va.x) | ((unsigned)f2bf(vb_.x) << 16);
    *(unsigned*)&Vt[(colq + 1) * LDT + s0] = (unsigned)f2bf(va.y) | ((unsigned)f2bf(vb_.y) << 16);
    *(unsigned*)&Vt[(colq + 2) * LDT + s0] = (unsigned)f2bf(va.z) | ((unsigned)f2bf(vb_.z) << 16);
    *(unsigned*)&Vt[(colq + 3) * LDT + s0] = (unsigned)f2bf(va.w) | ((unsigned)f2bf(vb_.w) << 16);
  }
  __syncthreads();
  // z[d] from bf16 K
  {
    const int zd = t >> 2, zg = t & 3;
    float zp = 0.f;
#pragma unroll
    for (int ss = 0; ss < 16; ++ss) zp += bf2f(Kt[zd * LDT + zg * 16 + ss]);
    zp += __shfl_xor(zp, 1, 64);
    zp += __shfl_xor(zp, 2, 64);
    if (zg == 0) zc[(size_t)(bh * 16 + c) * 64 + zd] = zp;
  }
  const int lane = t & 63, wid = t >> 6;
  const int wr = wid >> 1, wc = wid & 1;
  const int l15 = lane & 15, lg = lane >> 4;
  bf16x8 av[2][2], bk[2][2];
#pragma unroll
  for (int kk = 0; kk < 2; ++kk) {
#pragma unroll
    for (int mm = 0; mm < 2; ++mm)
      av[kk][mm] = *(const bf16x8*)&Vt[(wr * 32 + mm * 16 + l15) * LDT + kk * 32 + lg * 8];
#pragma unroll
    for (int nn = 0; nn < 2; ++nn)
      bk[kk][nn] = *(const bf16x8*)&Kt[(wc * 32 + nn * 16 + l15) * LDT + kk * 32 + lg * 8];
  }
  f32x4v acc[2][2] = {};
#pragma unroll
  for (int kk = 0; kk < 2; ++kk)
#pragma unroll
    for (int mm = 0; mm < 2; ++mm)
#pragma unroll
      for (int nn = 0; nn < 2; ++nn)
        acc[mm][nn] = __builtin_amdgcn_mfma_f32_16x16x32_bf16(av[kk][mm], bk[kk][nn], acc[mm][nn], 0, 0, 0);
  float* kvout = KVc + (size_t)(bh * 16 + c) * 4096;
#pragma unroll
  for (int mm = 0; mm < 2; ++mm)
#pragma unroll
    for (int r = 0; r < 4; ++r) {
      const int row = wr * 32 + mm * 16 + lg * 4 + r;
#pragma unroll
      for (int nn = 0; nn < 2; ++nn) {
        const int col = wc * 32 + nn * 16 + l15;
        kvout[row * 64 + col] = acc[mm][nn][r];
      }
    }
}

// ---------------------------------------------------------------------------
// Exclusive prefix over 16 chunks per cell + totals.  grid (grp=16, bh=16)
// ---------------------------------------------------------------------------
__global__ __launch_bounds__(256) void lin_scan_exclusive(
    float* __restrict__ KVc, float* __restrict__ zc,
    float* __restrict__ KVtot, float* __restrict__ ztot)
{
  const int grp = blockIdx.x, bh = blockIdx.y, t = threadIdx.x;
  const size_t base = (size_t)bh * 16 * 4096 + grp * 256 + t;
  float run = 0.f;
#pragma unroll
  for (int c = 0; c < 16; ++c) {
    const float tmp = KVc[base + (size_t)c * 4096];
    KVc[base + (size_t)c * 4096] = run;
    run += tmp;
  }
  KVtot[(size_t)bh * 4096 + grp * 256 + t] = run;
  if (grp == 0 && t < 64) {
    const size_t zb = (size_t)bh * 16 * 64 + t;
    float rz = 0.f;
#pragma unroll
    for (int c = 0; c < 16; ++c) {
      const float tmp = zc[zb + c * 64];
      zc[zb + c * 64] = rz;
      rz += tmp;
    }
    ztot[bh * 64 + t] = rz;
  }
}

// ---------------------------------------------------------------------------
// SA apply (MFMA): S=Q@K^T masked; O = S@V + Q@KVprefix; den = rowsum(S)+Q.zp
// ---------------------------------------------------------------------------
__global__ __launch_bounds__(256) void sa_apply_mfma(
    const float* __restrict__ qbuf, const float* __restrict__ kbuf,
    const float* __restrict__ vbuf, const float* __restrict__ KVc,
    const float* __restrict__ zc, u16* __restrict__ out)
{
  constexpr int LDT = 72;
  __shared__ __align__(16) u16 Qs[64 * LDT];   // [i][d]
  __shared__ __align__(16) u16 Ks[64 * LDT];   // [j][d]
  __shared__ __align__(16) u16 Vt[64 * LDT];   // [m][j]
  __shared__ __align__(16) u16 Ps[64 * LDT];   // [i][j]
  __shared__ __align__(16) u16 KVs[64 * LDT];  // [m][d]
  __shared__ float zp[64];
  __shared__ float den1[2][64];
  __shared__ float den2[64];
  const int c = blockIdx.x, bh = blockIdx.y;
  const int b = bh >> 3, h = bh & 7;
  const int t = threadIdx.x;
  const size_t rowbase = (size_t)(b * 1024 + c * 64);
  // natural stages: Qs, Ks, KVs
  {
    const int srow = t >> 2, scg = (t & 3) * 16;
    const float* qp = &qbuf[(rowbase + srow) * 512 + h * 64 + scg];
    const float* kp = &kbuf[(rowbase + srow) * 512 + h * 64 + scg];
    const float* kvp = KVc + (size_t)(bh * 16 + c) * 4096 + srow * 64 + scg;
#pragma unroll
    for (int i = 0; i < 4; ++i) {
      const float4 a = *(const float4*)&qp[i * 4];
      *(ushort4*)&Qs[srow * LDT + scg + i * 4] = make_ushort4(f2bf(a.x), f2bf(a.y), f2bf(a.z), f2bf(a.w));
      const float4 bb = *(const float4*)&kp[i * 4];
      *(ushort4*)&Ks[srow * LDT + scg + i * 4] = make_ushort4(f2bf(bb.x), f2bf(bb.y), f2bf(bb.z), f2bf(bb.w));
      const float4 cc = *(const float4*)&kvp[i * 4];
      *(ushort4*)&KVs[srow * LDT + scg + i * 4] = make_ushort4(f2bf(cc.x), f2bf(cc.y), f2bf(cc.z), f2bf(cc.w));
    }
  }
  // transpose-stage V -> Vt[m][j]
  {
    const int sp = t >> 4, colq = (t & 15) * 4;
#pragma unroll
    for (int pp = 0; pp < 2; ++pp) {
      const int s0 = pp * 32 + 2 * sp;
      const float4 va = *(const float4*)&vbuf[(rowbase + s0) * 512 + h * 64 + colq];
      const float4 vb_ = *(const float4*)&vbuf[(rowbase + s0 + 1) * 512 + h * 64 + colq];
      *(unsigned*)&Vt[(colq + 0) * LDT + s0] = (unsigned)f2bf(va.x) | ((unsigned)f2bf(vb_.x) << 16);
      *(unsigned*)&Vt[(colq + 1) * LDT + s0] = (unsigned)f2bf(va.y) | ((unsigned)f2bf(vb_.y) << 16);
      *(unsigned*)&Vt[(colq + 2) * LDT + s0] = (unsigned)f2bf(va.z) | ((unsigned)f2bf(vb_.z) << 16);
      *(unsigned*)&Vt[(colq + 3) * LDT + s0] = (unsigned)f2bf(va.w) | ((unsigned)f2bf(vb_.w) << 16);
    }
  }
  if (t < 64) zp[t] = zc[(size_t)(bh * 16 + c) * 64 + t];
  __syncthreads();
  // den2[i] = Q[i].zp
  {
    const int di = t >> 2, dg = t & 3;
    float p2 = 0.f;
#pragma unroll
    for (int dd = 0; dd < 16; ++dd)
      p2 += bf2f(Qs[di * LDT + dg * 16 + dd]) * zp[dg * 16 + dd];
    p2 += __shfl_xor(p2, 1, 64);
    p2 += __shfl_xor(p2, 2, 64);
    if (dg == 0) den2[di] = p2;
  }
  const int lane = t & 63, wid = t >> 6;
  const int wr = wid >> 1, wc = wid & 1;
  const int l15 = lane & 15, lg = lane >> 4;
  // Phase A: S = Q @ K^T
  bf16x8 af_q[2][2], bx[2][2];
#pragma unroll
  for (int kk = 0; kk < 2; ++kk) {
#pragma unroll
    for (int mm = 0; mm < 2; ++mm)
      af_q[kk][mm] = *(const bf16x8*)&Qs[(wr * 32 + mm * 16 + l15) * LDT + kk * 32 + lg * 8];
#pragma unroll
    for (int nn = 0; nn < 2; ++nn)
      bx[kk][nn] = *(const bf16x8*)&Ks[(wc * 32 + nn * 16 + l15) * LDT + kk * 32 + lg * 8];
  }
  f32x4v s_acc[2][2] = {};
#pragma unroll
  for (int kk = 0; kk < 2; ++kk)
#pragma unroll
    for (int mm = 0; mm < 2; ++mm)
#pragma unroll
      for (int nn = 0; nn < 2; ++nn)
        s_acc[mm][nn] = __builtin_amdgcn_mfma_f32_16x16x32_bf16(af_q[kk][mm], bx[kk][nn], s_acc[mm][nn], 0, 0, 0);
  // mask, P write, den1
#pragma unroll
  for (int mm = 0; mm < 2; ++mm)
#pragma unroll
    for (int r = 0; r < 4; ++r) {
      const int row = wr * 32 + mm * 16 + lg * 4 + r;
      float dsum = 0.f;
#pragma unroll
      for (int nn = 0; nn < 2; ++nn) {
        const int col = wc * 32 + nn * 16 + l15;
        const float val = (col <= row) ? s_acc[mm][nn][r] : 0.f;
        Ps[row * LDT + col] = f2bf(val);
        dsum += val;
      }
      dsum += __shfl_xor(dsum, 1, 64);
      dsum += __shfl_xor(dsum, 2, 64);
      dsum += __shfl_xor(dsum, 4, 64);
      dsum += __shfl_xor(dsum, 8, 64);
      if (l15 == 0) den1[wc][row] = dsum;
    }
  __syncthreads();
  // Phase B: O = P @ V  +  Q @ KVprefix
  bf16x8 ap[2][2];
#pragma unroll
  for (int kk = 0; kk < 2; ++kk) {
#pragma unroll
    for (int mm = 0; mm < 2; ++mm)
      ap[kk][mm] = *(const bf16x8*)&Ps[(wr * 32 + mm * 16 + l15) * LDT + kk * 32 + lg * 8];
#pragma unroll
    for (int nn = 0; nn < 2; ++nn)
      bx[kk][nn] = *(const bf16x8*)&Vt[(wc * 32 + nn * 16 + l15) * LDT + kk * 32 + lg * 8];
  }
  f32x4v o_acc[2][2] = {};
#pragma unroll
  for (int kk = 0; kk < 2; ++kk)
#pragma unroll
    for (int mm = 0; mm < 2; ++mm)
#pragma unroll
      for (int nn = 0; nn < 2; ++nn)
        o_acc[mm][nn] = __builtin_amdgcn_mfma_f32_16x16x32_bf16(ap[kk][mm], bx[kk][nn], o_acc[mm][nn], 0, 0, 0);
#pragma unroll
  for (int kk = 0; kk < 2; ++kk)
#pragma unroll
    for (int nn = 0; nn < 2; ++nn)
      bx[kk][nn] = *(const bf16x8*)&KVs[(wc * 32 + nn * 16 + l15) * LDT + kk * 32 + lg * 8];
#pragma unroll
  for (int kk = 0; kk < 2; ++kk)
#pragma unroll
    for (int mm = 0; mm < 2; ++mm)
#pragma unroll
      for (int nn = 0; nn < 2; ++nn)
        o_acc[mm][nn] = __builtin_amdgcn_mfma_f32_16x16x32_bf16(af_q[kk][mm], bx[kk][nn], o_acc[mm][nn], 0, 0, 0);
  // epilogue
#pragma unroll
  for (int mm = 0; mm < 2; ++mm)
#pragma unroll
    for (int r = 0; r < 4; ++r) {
      const int row = wr * 32 + mm * 16 + lg * 4 + r;
      const float rden = 1.f / (den1[0][row] + den1[1][row] + den2[row] + 1e-6f);
#pragma unroll
      for (int nn = 0; nn < 2; ++nn) {
        const int col = wc * 32 + nn * 16 + l15;
        out[(rowbase + row) * 512 + h * 64 + col] = f2bf(o_acc[mm][nn][r] * rden);
      }
    }
}

// ---------------------------------------------------------------------------
// CA apply (MFMA): O = Q @ KVtot / (Q.ztot + eps)
// ---------------------------------------------------------------------------
__global__ __launch_bounds__(256) void ca_apply_mfma(
    const float* __restrict__ qbuf, const float* __restrict__ KVtot,
    const float* __restrict__ ztot, u16* __restrict__ out)
{
  constexpr int LDT = 72;
  __shared__ __align__(16) u16 Qs[64 * LDT];
  __shared__ __align__(16) u16 KVs[64 * LDT];
  __shared__ float zt[64];
  __shared__ float den2[64];
  const int c = blockIdx.x, bh = blockIdx.y;
  const int b = bh >> 3, h = bh & 7;
  const int t = threadIdx.x;
  const size_t rowbase = (size_t)(b * 1024 + c * 64);
  {
    const int srow = t >> 2, scg = (t & 3) * 16;
    const float* qp = &qbuf[(rowbase + srow) * 512 + h * 64 + scg];
    const float* kvp = KVtot + (size_t)bh * 4096 + srow * 64 + scg;
#pragma unroll
    for (int i = 0; i < 4; ++i) {
      const float4 a = *(const float4*)&qp[i * 4];
      *(ushort4*)&Qs[srow * LDT + scg + i * 4] = make_ushort4(f2bf(a.x), f2bf(a.y), f2bf(a.z), f2bf(a.w));
      const float4 cc = *(const float4*)&kvp[i * 4];
      *(ushort4*)&KVs[srow * LDT + scg + i * 4] = make_ushort4(f2bf(cc.x), f2bf(cc.y), f2bf(cc.z), f2bf(cc.w));
    }
  }
  if (t < 64) zt[t] = ztot[bh * 64 + t];
  __syncthreads();
  {
    const int di = t >> 2, dg = t & 3;
    float p2 = 0.f;
#pragma unroll
    for (int dd = 0; dd < 16; ++dd)
      p2 += bf2f(Qs[di * LDT + dg * 16 + dd]) * zt[dg * 16 + dd];
    p2 += __shfl_xor(p2, 1, 64);
    p2 += __shfl_xor(p2, 2, 64);
    if (dg == 0) den2[di] = p2;
  }
  const int lane = t & 63, wid = t >> 6;
  const int wr = wid >> 1, wc = wid & 1;
  const int l15 = lane & 15, lg = lane >> 4;
  bf16x8 aq[2][2], bkv[2][2];
#pragma unroll
  for (int kk = 0; kk < 2; ++kk) {
#pragma unroll
    for (int mm = 0; mm < 2; ++mm)
      aq[kk][mm] = *(const bf16x8*)&Qs[(wr * 32 + mm * 16 + l15) * LDT + kk * 32 + lg * 8];
#pragma unroll
    for (int nn = 0; nn < 2; ++nn)
      bkv[kk][nn] = *(const bf16x8*)&KVs[(wc * 32 + nn * 16 + l15) * LDT + kk * 32 + lg * 8];
  }
  f32x4v o_acc[2][2] = {};
#pragma unroll
  for (int kk = 0; kk < 2; ++kk)
#pragma unroll
    for (int mm = 0; mm < 2; ++mm)
#pragma unroll
      for (int nn = 0; nn < 2; ++nn)
        o_acc[mm][nn] = __builtin_amdgcn_mfma_f32_16x16x32_bf16(aq[kk][mm], bkv[kk][nn], o_acc[mm][nn], 0, 0, 0);
  __syncthreads();
#pragma unroll
  for (int mm = 0; mm < 2; ++mm)
#pragma unroll
    for (int r = 0; r < 4; ++r) {
      const int row = wr * 32 + mm * 16 + lg * 4 + r;
      const float rden = 1.f / (den2[row] + 1e-6f);
#pragma unroll
      for (int nn = 0; nn < 2; ++nn) {
        const int col = wc * 32 + nn * 16 + l15;
        out[(rowbase + row) * 512 + h * 64 + col] = f2bf(o_acc[mm][nn][r] * rden);
      }
    }
}

// ---------------------------------------------------------------------------
// LayerNorm: x = LN(x + a) in place (f32). 1 wave per row, 4 rows/block
// ---------------------------------------------------------------------------
__global__ __launch_bounds__(256) void ln_residual(
    float* __restrict__ x, const float* __restrict__ a,
    const float* __restrict__ g, const float* __restrict__ bt)
{
  const int t = threadIdx.x, lane = t & 63, w = t >> 6;
  const int row = blockIdx.x * 4 + w;
  float* xr = x + (size_t)row * 512;
  const float* ar = a + (size_t)row * 512;
  float4 x0 = *(const float4*)&xr[lane * 8];
  float4 x1 = *(const float4*)&xr[lane * 8 + 4];
  float4 a0 = *(const float4*)&ar[lane * 8];
  float4 a1 = *(const float4*)&ar[lane * 8 + 4];
  float v[8];
  v[0] = x0.x + a0.x; v[1] = x0.y + a0.y; v[2] = x0.z + a0.z; v[3] = x0.w + a0.w;
  v[4] = x1.x + a1.x; v[5] = x1.y + a1.y; v[6] = x1.z + a1.z; v[7] = x1.w + a1.w;
  float s = 0.f, sq = 0.f;
#pragma unroll
  for (int i = 0; i < 8; ++i) { s += v[i]; sq += v[i] * v[i]; }
#pragma unroll
  for (int off = 32; off > 0; off >>= 1) {
    s += __shfl_xor(s, off, 64);
    sq += __shfl_xor(sq, off, 64);
  }
  const float mean = s * (1.f / 512.f);
  const float var = sq * (1.f / 512.f) - mean * mean;
  const float rstd = rsqrtf(var + 1e-5f);
  float o[8];
#pragma unroll
  for (int i = 0; i < 8; ++i) {
    const int col = lane * 8 + i;
    o[i] = (v[i] - mean) * rstd * g[col] + bt[col];
  }
  *(float4*)&xr[lane * 8]     = make_float4(o[0], o[1], o[2], o[3]);
  *(float4*)&xr[lane * 8 + 4] = make_float4(o[4], o[5], o[6], o[7]);
}

__global__ __launch_bounds__(256) void ln_final(
    const float* __restrict__ x, const float* __restrict__ g,
    const float* __restrict__ bt, float* __restrict__ out)
{
  const int t = threadIdx.x, lane = t & 63, w = t >> 6;
  const int row = blockIdx.x * 4 + w;
  const float* xr = x + (size_t)row * 512;
  float4 x0 = *(const float4*)&xr[lane * 8];
  float4 x1 = *(const float4*)&xr[lane * 8 + 4];
  float v[8] = { x0.x, x0.y, x0.z, x0.w, x1.x, x1.y, x1.z, x1.w };
  float s = 0.f, sq = 0.f;
#pragma unroll
  for (int i = 0; i < 8; ++i) { s += v[i]; sq += v[i] * v[i]; }
#pragma unroll
  for (int off = 32; off > 0; off >>= 1) {
    s += __shfl_xor(s, off, 64);
    sq += __shfl_xor(sq, off, 64);
  }
  const float mean = s * (1.f / 512.f);
  const float var = sq * (1.f / 512.f) - mean * mean;
  const float rstd = rsqrtf(var + 1e-5f);
  float o[8];
#pragma unroll
  for (int i = 0; i < 8; ++i) {
    const int col = lane * 8 + i;
    o[i] = (v[i] - mean) * rstd * g[col] + bt[col];
  }
  *(float4*)&out[(size_t)row * 512 + lane * 8]     = make_float4(o[0], o[1], o[2], o[3]);
  *(float4*)&out[(size_t)row * 512 + lane * 8 + 4] = make_float4(o[4], o[5], o[6], o[7]);
}

// ---------------------------------------------------------------------------
extern "C" void kernel_launch(void* const* d_in, const int* in_sizes, int n_in,
                              void* d_out, int out_size, void* d_ws, size_t ws_size,
                              hipStream_t stream)
{
  (void)in_sizes; (void)n_in; (void)out_size; (void)ws_size;
  constexpr int Dm = 512, Lc = 4, FFc = 2048;

  const float* memory = (const float*)d_in[0];
  const float* target = (const float*)d_in[1];
  const float *saW[4], *sab[4], *caW[4], *cab[4];
  for (int j = 0; j < 4; ++j) {
    saW[j] = (const float*)d_in[2 + 2 * j];
    sab[j] = (const float*)d_in[3 + 2 * j];
    caW[j] = (const float*)d_in[10 + 2 * j];
    cab[j] = (const float*)d_in[11 + 2 * j];
  }
  const float* ffW1 = (const float*)d_in[18];
  const float* ffb1 = (const float*)d_in[19];
  const float* ffW2 = (const float*)d_in[20];
  const float* ffb2 = (const float*)d_in[21];
  const float* lng[4] = { (const float*)d_in[22], (const float*)d_in[24],
                          (const float*)d_in[26], (const float*)d_in[28] };
  const float* lnb[4] = { (const float*)d_in[23], (const float*)d_in[25],
                          (const float*)d_in[27], (const float*)d_in[29] };

  size_t off = 0;
  auto alloc = [&](size_t bytes) -> void* {
    void* p = (char*)d_ws + off;
    off += (bytes + 255) & ~(size_t)255;
    return p;
  };
  u16* WtS[4]; u16* WtC[4];
  for (int j = 0; j < 4; ++j) WtS[j] = (u16*)alloc((size_t)Lc * Dm * Dm * 2);
  for (int j = 0; j < 4; ++j) WtC[j] = (u16*)alloc((size_t)Lc * Dm * Dm * 2);
  u16* WtF1 = (u16*)alloc((size_t)Lc * Dm * FFc * 2);
  u16* WtF2 = (u16*)alloc((size_t)Lc * FFc * Dm * 2);
  float* x    = (float*)alloc((size_t)2048 * 512 * 4);
  float* qb   = (float*)alloc((size_t)2048 * 512 * 4);
  float* kb   = (float*)alloc((size_t)2048 * 512 * 4);
  float* vb   = (float*)alloc((size_t)2048 * 512 * 4);
  u16*   attn = (u16*)alloc((size_t)2048 * 512 * 2);
  u16*   ffh  = (u16*)alloc((size_t)2048 * 2048 * 2);
  float* KVc  = (float*)alloc((size_t)16 * 16 * 4096 * 4);
  float* zcb  = (float*)alloc((size_t)16 * 16 * 64 * 4);
  float* KVtot= (float*)alloc((size_t)16 * 4096 * 4);
  float* ztot = (float*)alloc((size_t)16 * 64 * 4);

  for (int j = 0; j < 4; ++j) {
    transpose_f2b<<<dim3(8, 8, 4), 256, 0, stream>>>(saW[j], WtS[j], Dm, Dm);
    transpose_f2b<<<dim3(8, 8, 4), 256, 0, stream>>>(caW[j], WtC[j], Dm, Dm);
  }
  transpose_f2b<<<dim3(32, 8, 4), 256, 0, stream>>>(ffW1, WtF1, Dm, FFc);
  transpose_f2b<<<dim3(8, 32, 4), 256, 0, stream>>>(ffW2, WtF2, FFc, Dm);

  hipMemcpyAsync(x, target, (size_t)2048 * 512 * 4, hipMemcpyDeviceToDevice, stream);

  for (int i = 0; i < Lc; ++i) {
    const size_t wo  = (size_t)i * Dm * Dm;
    const size_t wo1 = (size_t)i * Dm * FFc;
    const size_t wo2 = (size_t)i * FFc * Dm;
    // ---- causal linear self-attention ----
    gemm64<0, 0><<<dim3(32, 24), 256, 0, stream>>>(
        x, x, x, WtS[0] + wo, WtS[1] + wo, WtS[2] + wo,
        sab[0] + i * Dm, sab[1] + i * Dm, sab[2] + i * Dm,
        qb, kb, vb, 0x05, 512, 512, 3);
    lin_chunk_mfma<<<dim3(16, 16), 256, 0, stream>>>(kb, vb, KVc, zcb);
    lin_scan_exclusive<<<dim3(16, 16), 256, 0, stream>>>(KVc, zcb, KVtot, ztot);
    sa_apply_mfma<<<dim3(16, 16), 256, 0, stream>>>(qb, kb, vb, KVc, zcb, attn);
    gemm64<1, 0><<<dim3(32, 8), 256, 0, stream>>>(
        attn, attn, attn, WtS[3] + wo, WtS[3] + wo, WtS[3] + wo,
        sab[3] + i * Dm, sab[3] + i * Dm, sab[3] + i * Dm,
        qb, qb, qb, 0, 512, 512, 3);
    ln_residual<<<512, 256, 0, stream>>>(x, qb, lng[0] + i * Dm, lnb[0] + i * Dm);
    // ---- linear cross-attention ----
    gemm64<0, 0><<<dim3(32, 24), 256, 0, stream>>>(
        x, memory, memory, WtC[0] + wo, WtC[1] + wo, WtC[2] + wo,
        cab[0] + i * Dm, cab[1] + i * Dm, cab[2] + i * Dm,
        qb, kb, vb, 0x05, 512, 512, 3);
    lin_chunk_mfma<<<dim3(16, 16), 256, 0, stream>>>(kb, vb, KVc, zcb);
    lin_scan_exclusive<<<dim3(16, 16), 256, 0, stream>>>(KVc, zcb, KVtot, ztot);
    ca_apply_mfma<<<dim3(16, 16), 256, 0, stream>>>(qb, KVtot, ztot, attn);
    gemm64<1, 0><<<dim3(32, 8), 256, 0, stream>>>(
        attn, attn, attn, WtC[3] + wo, WtC[3] + wo, WtC[3] + wo,
        cab[3] + i * Dm, cab[3] + i * Dm, cab[3] + i * Dm,
        qb, qb, qb, 0, 512, 512, 3);
    ln_residual<<<512, 256, 0, stream>>>(x, qb, lng[1] + i * Dm, lnb[1] + i * Dm);
    // ---- FFN ----
    gemm64<0, 1><<<dim3(32, 32), 256, 0, stream>>>(
        x, x, x, WtF1 + wo1, WtF1 + wo1, WtF1 + wo1,
        ffb1 + i * FFc, ffb1 + i * FFc, ffb1 + i * FFc,
        ffh, ffh, ffh, 2, 2048, 512, 5);
    gemm64<1, 0><<<dim3(32, 8), 256, 0, stream>>>(
        ffh, ffh, ffh, WtF2 + wo2, WtF2 + wo2, WtF2 + wo2,
        ffb2 + i * Dm, ffb2 + i * Dm, ffb2 + i * Dm,
        qb, qb, qb, 0, 512, 2048, 3);
    ln_residual<<<512, 256, 0, stream>>>(x, qb, lng[2] + i * Dm, lnb[2] + i * Dm);
  }
  ln_final<<<512, 256, 0, stream>>>(x, lng[3], lnb[3], (float*)d_out);
}

// Round 6
// 605.612 us; speedup vs baseline: 2.8305x; 1.1263x over previous
//
#include <hip/hip_runtime.h>
#include <hip/hip_bf16.h>
#include <math.h>

// ---------------------------------------------------------------------------
// LinearTransformerCausalDecoder on MI355X (gfx950)
// B=2, S=M=1024, D=512, H=8, HD=64, L=4, FF=2048
// d_in / d_out are FLOAT32. Weights pre-transposed to bf16 Wt[N][K] once.
// All GEMM operands bf16 (activations cast once, not per-tile). Residual
// stream kept f32. GEMM: 64x64 tile, dbuf LDS, 1 barrier/K-step.
// ---------------------------------------------------------------------------

typedef unsigned short u16;
typedef __bf16 bf16x8 __attribute__((ext_vector_type(8)));
typedef float f32x4v __attribute__((ext_vector_type(4)));

#define DEVI __device__ __forceinline__

DEVI float bf2f(u16 u) { return __uint_as_float(((unsigned)u) << 16); }
DEVI u16 f2bf(float f) {
  unsigned u = __float_as_uint(f);
  u += 0x7FFFu + ((u >> 16) & 1u);   // RNE
  return (u16)(u >> 16);
}

// ---------------------------------------------------------------------------
// Weight transpose+convert: in f32 [mat][K][N] -> out bf16 [mat][N][K]
// ---------------------------------------------------------------------------
__global__ __launch_bounds__(256) void transpose_f2b(
    const float* __restrict__ in, u16* __restrict__ out, int K, int N)
{
  __shared__ float tile[64 * 65];
  const size_t mat = (size_t)blockIdx.z * K * N;
  const int n0 = blockIdx.x * 64, k0 = blockIdx.y * 64;
  const int t = threadIdx.x;
#pragma unroll
  for (int p = 0; p < 16; ++p) {
    const int e = t + p * 256;
    const int lk = e >> 6, ln = e & 63;
    tile[lk * 65 + ln] = in[mat + (size_t)(k0 + lk) * N + n0 + ln];
  }
  __syncthreads();
#pragma unroll
  for (int p = 0; p < 16; ++p) {
    const int e = t + p * 256;
    const int ln = e >> 6, lk = e & 63;
    out[mat + (size_t)(n0 + ln) * K + k0 + lk] = f2bf(tile[lk * 65 + ln]);
  }
}

// f32 -> (optional f32 copy) + bf16, 8 elems/thread, 1M elements (512 blocks)
__global__ __launch_bounds__(256) void cast_dual(
    const float* __restrict__ in, float* __restrict__ fout, u16* __restrict__ bout)
{
  const int i = blockIdx.x * 256 + threadIdx.x;
  const float4 a = ((const float4*)in)[i * 2];
  const float4 b = ((const float4*)in)[i * 2 + 1];
  if (fout) {
    ((float4*)fout)[i * 2] = a;
    ((float4*)fout)[i * 2 + 1] = b;
  }
  ((ushort4*)bout)[i * 2]     = make_ushort4(f2bf(a.x), f2bf(a.y), f2bf(a.z), f2bf(a.w));
  ((ushort4*)bout)[i * 2 + 1] = make_ushort4(f2bf(b.x), f2bf(b.y), f2bf(b.z), f2bf(b.w));
}

// ---------------------------------------------------------------------------
// Fused multi-segment GEMM, all-bf16 operands, double-buffered LDS.
//   C_s = act_s(A_s[M][K] @ Wt_s^T + b_s)   A,Wt bf16;  CDT: 0 C=f32, 1 C=bf16
// Tile 64x64, BK=64, 4 waves (2x2). acts: 2 bits/segment (0 none,1 phi,2 gelu).
// ---------------------------------------------------------------------------
template<int CDT>
__global__ __launch_bounds__(256, 4) void gemm64(
    const u16* __restrict__ A0, const u16* __restrict__ A1, const u16* __restrict__ A2,
    const u16* __restrict__ W0, const u16* __restrict__ W1, const u16* __restrict__ W2,
    const float* __restrict__ b0, const float* __restrict__ b1, const float* __restrict__ b2,
    void* __restrict__ C0, void* __restrict__ C1, void* __restrict__ C2,
    int acts, int N, int K, int lognyb)
{
  constexpr int LDT = 72;
  __shared__ __align__(16) u16 As[2][64 * LDT];
  __shared__ __align__(16) u16 Bs[2][64 * LDT];
  const int tid = threadIdx.x;
  const int by = blockIdx.y;
  const int seg = by >> lognyb;
  const int ny = by & ((1 << lognyb) - 1);
  const u16* A = seg == 0 ? A0 : (seg == 1 ? A1 : A2);
  const u16* W = seg == 0 ? W0 : (seg == 1 ? W1 : W2);
  const float* bias = seg == 0 ? b0 : (seg == 1 ? b1 : b2);
  void* Cv = seg == 0 ? C0 : (seg == 1 ? C1 : C2);
  const int act = (acts >> (2 * seg)) & 3;

  const int bm0 = blockIdx.x * 64, bn0 = ny * 64;
  const int lane = tid & 63, wid = tid >> 6;
  const int wr = wid >> 1, wc = wid & 1;
  const int l15 = lane & 15, lg = lane >> 4;
  const int srow = tid >> 2, scg = (tid & 3) * 16;
  const u16* Ap = A + (size_t)(bm0 + srow) * K + scg;
  const u16* Wp = W + (size_t)(bn0 + srow) * K + scg;

  // prologue: stage tile 0
  uint4 ra0 = *(const uint4*)(Ap);
  uint4 ra1 = *(const uint4*)(Ap + 8);
  uint4 rb0 = *(const uint4*)(Wp);
  uint4 rb1 = *(const uint4*)(Wp + 8);
  *(uint4*)&As[0][srow * LDT + scg]     = ra0;
  *(uint4*)&As[0][srow * LDT + scg + 8] = ra1;
  *(uint4*)&Bs[0][srow * LDT + scg]     = rb0;
  *(uint4*)&Bs[0][srow * LDT + scg + 8] = rb1;
  __syncthreads();

  f32x4v acc[2][2] = {};
  int cur = 0;
  for (int k0 = 0; k0 < K; k0 += 64) {
    const bool more = (k0 + 64 < K);
    if (more) {                 // issue next-tile loads; land after MFMAs
      ra0 = *(const uint4*)(Ap + k0 + 64);
      ra1 = *(const uint4*)(Ap + k0 + 72);
      rb0 = *(const uint4*)(Wp + k0 + 64);
      rb1 = *(const uint4*)(Wp + k0 + 72);
    }
    bf16x8 af[2][2], bw[2][2];
#pragma unroll
    for (int kk = 0; kk < 2; ++kk) {
#pragma unroll
      for (int mm = 0; mm < 2; ++mm)
        af[kk][mm] = *(const bf16x8*)&As[cur][(wr * 32 + mm * 16 + l15) * LDT + kk * 32 + lg * 8];
#pragma unroll
      for (int nn = 0; nn < 2; ++nn)
        bw[kk][nn] = *(const bf16x8*)&Bs[cur][(wc * 32 + nn * 16 + l15) * LDT + kk * 32 + lg * 8];
    }
#pragma unroll
    for (int kk = 0; kk < 2; ++kk)
#pragma unroll
      for (int mm = 0; mm < 2; ++mm)
#pragma unroll
        for (int nn = 0; nn < 2; ++nn)
          acc[mm][nn] = __builtin_amdgcn_mfma_f32_16x16x32_bf16(af[kk][mm], bw[kk][nn], acc[mm][nn], 0, 0, 0);
    if (more) {
      *(uint4*)&As[cur ^ 1][srow * LDT + scg]     = ra0;
      *(uint4*)&As[cur ^ 1][srow * LDT + scg + 8] = ra1;
      *(uint4*)&Bs[cur ^ 1][srow * LDT + scg]     = rb0;
      *(uint4*)&Bs[cur ^ 1][srow * LDT + scg + 8] = rb1;
    }
    __syncthreads();
    cur ^= 1;
  }
#pragma unroll
  for (int nn = 0; nn < 2; ++nn) {
    const int col = bn0 + wc * 32 + nn * 16 + l15;
    const float bv = bias[col];
#pragma unroll
    for (int mm = 0; mm < 2; ++mm) {
#pragma unroll
      for (int r = 0; r < 4; ++r) {
        const int row = bm0 + wr * 32 + mm * 16 + lg * 4 + r;
        float v = acc[mm][nn][r] + bv;
        if (act == 1) v = v > 0.f ? v + 1.f : __expf(v);
        else if (act == 2) v = 0.5f * v * (1.f + erff(v * 0.70710678f));
        if (CDT == 0) ((float*)Cv)[(size_t)row * N + col] = v;
        else          ((u16*)Cv)[(size_t)row * N + col] = f2bf(v);
      }
    }
  }
}

// ---------------------------------------------------------------------------
// Chunk sums (MFMA): per (c,bh): KVt[m][d] = sum_s V[s][m]*K[s][d] (f32 out),
// z[d] = sum_s K[s][d].  Inputs bf16.
// ---------------------------------------------------------------------------
__global__ __launch_bounds__(256) void lin_chunk_mfma(
    const u16* __restrict__ kbuf, const u16* __restrict__ vbuf,
    float* __restrict__ KVc, float* __restrict__ zc)
{
  constexpr int LDT = 72;
  __shared__ __align__(16) u16 Kt[64 * LDT];   // Kt[d][s]
  __shared__ __align__(16) u16 Vt[64 * LDT];   // Vt[m][s]
  const int c = blockIdx.x, bh = blockIdx.y;
  const int b = bh >> 3, h = bh & 7;
  const int t = threadIdx.x;
  const size_t rowbase = (size_t)(b * 1024 + c * 64);
  const int sp = t >> 4, colq = (t & 15) * 4;
#pragma unroll
  for (int pp = 0; pp < 2; ++pp) {
    const int s0 = pp * 32 + 2 * sp;
    const ushort4 ka = *(const ushort4*)&kbuf[(rowbase + s0) * 512 + h * 64 + colq];
    const ushort4 kb_ = *(const ushort4*)&kbuf[(rowbase + s0 + 1) * 512 + h * 64 + colq];
    const ushort4 va = *(const ushort4*)&vbuf[(rowbase + s0) * 512 + h * 64 + colq];
    const ushort4 vb_ = *(const ushort4*)&vbuf[(rowbase + s0 + 1) * 512 + h * 64 + colq];
    *(unsigned*)&Kt[(colq + 0) * LDT + s0] = (unsigned)ka.x | ((unsigned)kb_.x << 16);
    *(unsigned*)&Kt[(colq + 1) * LDT + s0] = (unsigned)ka.y | ((unsigned)kb_.y << 16);
    *(unsigned*)&Kt[(colq + 2) * LDT + s0] = (unsigned)ka.z | ((unsigned)kb_.z << 16);
    *(unsigned*)&Kt[(colq + 3) * LDT + s0] = (unsigned)ka.w | ((unsigned)kb_.w << 16);
    *(unsigned*)&Vt[(colq + 0) * LDT + s0] = (unsigned)va.x | ((unsigned)vb_.x << 16);
    *(unsigned*)&Vt[(colq + 1) * LDT + s0] = (unsigned)va.y | ((unsigned)vb_.y << 16);
    *(unsigned*)&Vt[(colq + 2) * LDT + s0] = (unsigned)va.z | ((unsigned)vb_.z << 16);
    *(unsigned*)&Vt[(colq + 3) * LDT + s0] = (unsigned)va.w | ((unsigned)vb_.w << 16);
  }
  __syncthreads();
  {
    const int zd = t >> 2, zg = t & 3;
    float zp = 0.f;
#pragma unroll
    for (int ss = 0; ss < 16; ++ss) zp += bf2f(Kt[zd * LDT + zg * 16 + ss]);
    zp += __shfl_xor(zp, 1, 64);
    zp += __shfl_xor(zp, 2, 64);
    if (zg == 0) zc[(size_t)(bh * 16 + c) * 64 + zd] = zp;
  }
  const int lane = t & 63, wid = t >> 6;
  const int wr = wid >> 1, wc = wid & 1;
  const int l15 = lane & 15, lg = lane >> 4;
  bf16x8 av[2][2], bk[2][2];
#pragma unroll
  for (int kk = 0; kk < 2; ++kk) {
#pragma unroll
    for (int mm = 0; mm < 2; ++mm)
      av[kk][mm] = *(const bf16x8*)&Vt[(wr * 32 + mm * 16 + l15) * LDT + kk * 32 + lg * 8];
#pragma unroll
    for (int nn = 0; nn < 2; ++nn)
      bk[kk][nn] = *(const bf16x8*)&Kt[(wc * 32 + nn * 16 + l15) * LDT + kk * 32 + lg * 8];
  }
  f32x4v acc[2][2] = {};
#pragma unroll
  for (int kk = 0; kk < 2; ++kk)
#pragma unroll
    for (int mm = 0; mm < 2; ++mm)
#pragma unroll
      for (int nn = 0; nn < 2; ++nn)
        acc[mm][nn] = __builtin_amdgcn_mfma_f32_16x16x32_bf16(av[kk][mm], bk[kk][nn], acc[mm][nn], 0, 0, 0);
  float* kvout = KVc + (size_t)(bh * 16 + c) * 4096;
#pragma unroll
  for (int mm = 0; mm < 2; ++mm)
#pragma unroll
    for (int r = 0; r < 4; ++r) {
      const int row = wr * 32 + mm * 16 + lg * 4 + r;
#pragma unroll
      for (int nn = 0; nn < 2; ++nn) {
        const int col = wc * 32 + nn * 16 + l15;
        kvout[row * 64 + col] = acc[mm][nn][r];
      }
    }
}

// ---------------------------------------------------------------------------
// Exclusive prefix over 16 chunks per cell + totals.  grid (grp=16, bh=16)
// ---------------------------------------------------------------------------
__global__ __launch_bounds__(256) void lin_scan_exclusive(
    float* __restrict__ KVc, float* __restrict__ zc,
    float* __restrict__ KVtot, float* __restrict__ ztot)
{
  const int grp = blockIdx.x, bh = blockIdx.y, t = threadIdx.x;
  const size_t base = (size_t)bh * 16 * 4096 + grp * 256 + t;
  float run = 0.f;
#pragma unroll
  for (int c = 0; c < 16; ++c) {
    const float tmp = KVc[base + (size_t)c * 4096];
    KVc[base + (size_t)c * 4096] = run;
    run += tmp;
  }
  KVtot[(size_t)bh * 4096 + grp * 256 + t] = run;
  if (grp == 0 && t < 64) {
    const size_t zb = (size_t)bh * 16 * 64 + t;
    float rz = 0.f;
#pragma unroll
    for (int c = 0; c < 16; ++c) {
      const float tmp = zc[zb + c * 64];
      zc[zb + c * 64] = rz;
      rz += tmp;
    }
    ztot[bh * 64 + t] = rz;
  }
}

// ---------------------------------------------------------------------------
// SA apply (MFMA): S=Q@K^T masked; O = S@V + Q@KVprefix; den = rowsum(S)+Q.zp
// q/k/v inputs bf16; out bf16.
// ---------------------------------------------------------------------------
__global__ __launch_bounds__(256) void sa_apply_mfma(
    const u16* __restrict__ qbuf, const u16* __restrict__ kbuf,
    const u16* __restrict__ vbuf, const float* __restrict__ KVc,
    const float* __restrict__ zc, u16* __restrict__ out)
{
  constexpr int LDT = 72;
  __shared__ __align__(16) u16 Qs[64 * LDT];   // [i][d]
  __shared__ __align__(16) u16 Ks[64 * LDT];   // [j][d]
  __shared__ __align__(16) u16 Vt[64 * LDT];   // [m][j]
  __shared__ __align__(16) u16 Ps[64 * LDT];   // [i][j]
  __shared__ __align__(16) u16 KVs[64 * LDT];  // [m][d]
  __shared__ float zp[64];
  __shared__ float den1[2][64];
  __shared__ float den2[64];
  const int c = blockIdx.x, bh = blockIdx.y;
  const int b = bh >> 3, h = bh & 7;
  const int t = threadIdx.x;
  const size_t rowbase = (size_t)(b * 1024 + c * 64);
  {
    const int srow = t >> 2, scg = (t & 3) * 16;
    *(uint4*)&Qs[srow * LDT + scg]     = *(const uint4*)&qbuf[(rowbase + srow) * 512 + h * 64 + scg];
    *(uint4*)&Qs[srow * LDT + scg + 8] = *(const uint4*)&qbuf[(rowbase + srow) * 512 + h * 64 + scg + 8];
    *(uint4*)&Ks[srow * LDT + scg]     = *(const uint4*)&kbuf[(rowbase + srow) * 512 + h * 64 + scg];
    *(uint4*)&Ks[srow * LDT + scg + 8] = *(const uint4*)&kbuf[(rowbase + srow) * 512 + h * 64 + scg + 8];
    const float* kvp = KVc + (size_t)(bh * 16 + c) * 4096 + srow * 64 + scg;
#pragma unroll
    for (int i = 0; i < 4; ++i) {
      const float4 cc = *(const float4*)&kvp[i * 4];
      *(ushort4*)&KVs[srow * LDT + scg + i * 4] = make_ushort4(f2bf(cc.x), f2bf(cc.y), f2bf(cc.z), f2bf(cc.w));
    }
  }
  {
    const int sp = t >> 4, colq = (t & 15) * 4;
#pragma unroll
    for (int pp = 0; pp < 2; ++pp) {
      const int s0 = pp * 32 + 2 * sp;
      const ushort4 va = *(const ushort4*)&vbuf[(rowbase + s0) * 512 + h * 64 + colq];
      const ushort4 vb_ = *(const ushort4*)&vbuf[(rowbase + s0 + 1) * 512 + h * 64 + colq];
      *(unsigned*)&Vt[(colq + 0) * LDT + s0] = (unsigned)va.x | ((unsigned)vb_.x << 16);
      *(unsigned*)&Vt[(colq + 1) * LDT + s0] = (unsigned)va.y | ((unsigned)vb_.y << 16);
      *(unsigned*)&Vt[(colq + 2) * LDT + s0] = (unsigned)va.z | ((unsigned)vb_.z << 16);
      *(unsigned*)&Vt[(colq + 3) * LDT + s0] = (unsigned)va.w | ((unsigned)vb_.w << 16);
    }
  }
  if (t < 64) zp[t] = zc[(size_t)(bh * 16 + c) * 64 + t];
  __syncthreads();
  {
    const int di = t >> 2, dg = t & 3;
    float p2 = 0.f;
#pragma unroll
    for (int dd = 0; dd < 16; ++dd)
      p2 += bf2f(Qs[di * LDT + dg * 16 + dd]) * zp[dg * 16 + dd];
    p2 += __shfl_xor(p2, 1, 64);
    p2 += __shfl_xor(p2, 2, 64);
    if (dg == 0) den2[di] = p2;
  }
  const int lane = t & 63, wid = t >> 6;
  const int wr = wid >> 1, wc = wid & 1;
  const int l15 = lane & 15, lg = lane >> 4;
  bf16x8 af_q[2][2], bx[2][2];
#pragma unroll
  for (int kk = 0; kk < 2; ++kk) {
#pragma unroll
    for (int mm = 0; mm < 2; ++mm)
      af_q[kk][mm] = *(const bf16x8*)&Qs[(wr * 32 + mm * 16 + l15) * LDT + kk * 32 + lg * 8];
#pragma unroll
    for (int nn = 0; nn < 2; ++nn)
      bx[kk][nn] = *(const bf16x8*)&Ks[(wc * 32 + nn * 16 + l15) * LDT + kk * 32 + lg * 8];
  }
  f32x4v s_acc[2][2] = {};
#pragma unroll
  for (int kk = 0; kk < 2; ++kk)
#pragma unroll
    for (int mm = 0; mm < 2; ++mm)
#pragma unroll
      for (int nn = 0; nn < 2; ++nn)
        s_acc[mm][nn] = __builtin_amdgcn_mfma_f32_16x16x32_bf16(af_q[kk][mm], bx[kk][nn], s_acc[mm][nn], 0, 0, 0);
#pragma unroll
  for (int mm = 0; mm < 2; ++mm)
#pragma unroll
    for (int r = 0; r < 4; ++r) {
      const int row = wr * 32 + mm * 16 + lg * 4 + r;
      float dsum = 0.f;
#pragma unroll
      for (int nn = 0; nn < 2; ++nn) {
        const int col = wc * 32 + nn * 16 + l15;
        const float val = (col <= row) ? s_acc[mm][nn][r] : 0.f;
        Ps[row * LDT + col] = f2bf(val);
        dsum += val;
      }
      dsum += __shfl_xor(dsum, 1, 64);
      dsum += __shfl_xor(dsum, 2, 64);
      dsum += __shfl_xor(dsum, 4, 64);
      dsum += __shfl_xor(dsum, 8, 64);
      if (l15 == 0) den1[wc][row] = dsum;
    }
  __syncthreads();
  bf16x8 ap[2][2];
#pragma unroll
  for (int kk = 0; kk < 2; ++kk) {
#pragma unroll
    for (int mm = 0; mm < 2; ++mm)
      ap[kk][mm] = *(const bf16x8*)&Ps[(wr * 32 + mm * 16 + l15) * LDT + kk * 32 + lg * 8];
#pragma unroll
    for (int nn = 0; nn < 2; ++nn)
      bx[kk][nn] = *(const bf16x8*)&Vt[(wc * 32 + nn * 16 + l15) * LDT + kk * 32 + lg * 8];
  }
  f32x4v o_acc[2][2] = {};
#pragma unroll
  for (int kk = 0; kk < 2; ++kk)
#pragma unroll
    for (int mm = 0; mm < 2; ++mm)
#pragma unroll
      for (int nn = 0; nn < 2; ++nn)
        o_acc[mm][nn] = __builtin_amdgcn_mfma_f32_16x16x32_bf16(ap[kk][mm], bx[kk][nn], o_acc[mm][nn], 0, 0, 0);
#pragma unroll
  for (int kk = 0; kk < 2; ++kk)
#pragma unroll
    for (int nn = 0; nn < 2; ++nn)
      bx[kk][nn] = *(const bf16x8*)&KVs[(wc * 32 + nn * 16 + l15) * LDT + kk * 32 + lg * 8];
#pragma unroll
  for (int kk = 0; kk < 2; ++kk)
#pragma unroll
    for (int mm = 0; mm < 2; ++mm)
#pragma unroll
      for (int nn = 0; nn < 2; ++nn)
        o_acc[mm][nn] = __builtin_amdgcn_mfma_f32_16x16x32_bf16(af_q[kk][mm], bx[kk][nn], o_acc[mm][nn], 0, 0, 0);
#pragma unroll
  for (int mm = 0; mm < 2; ++mm)
#pragma unroll
    for (int r = 0; r < 4; ++r) {
      const int row = wr * 32 + mm * 16 + lg * 4 + r;
      const float rden = 1.f / (den1[0][row] + den1[1][row] + den2[row] + 1e-6f);
#pragma unroll
      for (int nn = 0; nn < 2; ++nn) {
        const int col = wc * 32 + nn * 16 + l15;
        out[(rowbase + row) * 512 + h * 64 + col] = f2bf(o_acc[mm][nn][r] * rden);
      }
    }
}

// ---------------------------------------------------------------------------
// CA apply (MFMA): O = Q @ KVtot / (Q.ztot + eps).  Q bf16.
// ---------------------------------------------------------------------------
__global__ __launch_bounds__(256) void ca_apply_mfma(
    const u16* __restrict__ qbuf, const float* __restrict__ KVtot,
    const float* __restrict__ ztot, u16* __restrict__ out)
{
  constexpr int LDT = 72;
  __shared__ __align__(16) u16 Qs[64 * LDT];
  __shared__ __align__(16) u16 KVs[64 * LDT];
  __shared__ float zt[64];
  __shared__ float den2[64];
  const int c = blockIdx.x, bh = blockIdx.y;
  const int b = bh >> 3, h = bh & 7;
  const int t = threadIdx.x;
  const size_t rowbase = (size_t)(b * 1024 + c * 64);
  {
    const int srow = t >> 2, scg = (t & 3) * 16;
    *(uint4*)&Qs[srow * LDT + scg]     = *(const uint4*)&qbuf[(rowbase + srow) * 512 + h * 64 + scg];
    *(uint4*)&Qs[srow * LDT + scg + 8] = *(const uint4*)&qbuf[(rowbase + srow) * 512 + h * 64 + scg + 8];
    const float* kvp = KVtot + (size_t)bh * 4096 + srow * 64 + scg;
#pragma unroll
    for (int i = 0; i < 4; ++i) {
      const float4 cc = *(const float4*)&kvp[i * 4];
      *(ushort4*)&KVs[srow * LDT + scg + i * 4] = make_ushort4(f2bf(cc.x), f2bf(cc.y), f2bf(cc.z), f2bf(cc.w));
    }
  }
  if (t < 64) zt[t] = ztot[bh * 64 + t];
  __syncthreads();
  {
    const int di = t >> 2, dg = t & 3;
    float p2 = 0.f;
#pragma unroll
    for (int dd = 0; dd < 16; ++dd)
      p2 += bf2f(Qs[di * LDT + dg * 16 + dd]) * zt[dg * 16 + dd];
    p2 += __shfl_xor(p2, 1, 64);
    p2 += __shfl_xor(p2, 2, 64);
    if (dg == 0) den2[di] = p2;
  }
  const int lane = t & 63, wid = t >> 6;
  const int wr = wid >> 1, wc = wid & 1;
  const int l15 = lane & 15, lg = lane >> 4;
  bf16x8 aq[2][2], bkv[2][2];
#pragma unroll
  for (int kk = 0; kk < 2; ++kk) {
#pragma unroll
    for (int mm = 0; mm < 2; ++mm)
      aq[kk][mm] = *(const bf16x8*)&Qs[(wr * 32 + mm * 16 + l15) * LDT + kk * 32 + lg * 8];
#pragma unroll
    for (int nn = 0; nn < 2; ++nn)
      bkv[kk][nn] = *(const bf16x8*)&KVs[(wc * 32 + nn * 16 + l15) * LDT + kk * 32 + lg * 8];
  }
  f32x4v o_acc[2][2] = {};
#pragma unroll
  for (int kk = 0; kk < 2; ++kk)
#pragma unroll
    for (int mm = 0; mm < 2; ++mm)
#pragma unroll
      for (int nn = 0; nn < 2; ++nn)
        o_acc[mm][nn] = __builtin_amdgcn_mfma_f32_16x16x32_bf16(aq[kk][mm], bkv[kk][nn], o_acc[mm][nn], 0, 0, 0);
  __syncthreads();
#pragma unroll
  for (int mm = 0; mm < 2; ++mm)
#pragma unroll
    for (int r = 0; r < 4; ++r) {
      const int row = wr * 32 + mm * 16 + lg * 4 + r;
      const float rden = 1.f / (den2[row] + 1e-6f);
#pragma unroll
      for (int nn = 0; nn < 2; ++nn) {
        const int col = wc * 32 + nn * 16 + l15;
        out[(rowbase + row) * 512 + h * 64 + col] = f2bf(o_acc[mm][nn][r] * rden);
      }
    }
}

// ---------------------------------------------------------------------------
// LayerNorm: x = LN(x + a) in place (f32) + bf16 mirror xb.
// ---------------------------------------------------------------------------
__global__ __launch_bounds__(256) void ln_residual(
    float* __restrict__ x, const float* __restrict__ a,
    const float* __restrict__ g, const float* __restrict__ bt,
    u16* __restrict__ xb)
{
  const int t = threadIdx.x, lane = t & 63, w = t >> 6;
  const int row = blockIdx.x * 4 + w;
  float* xr = x + (size_t)row * 512;
  const float* ar = a + (size_t)row * 512;
  float4 x0 = *(const float4*)&xr[lane * 8];
  float4 x1 = *(const float4*)&xr[lane * 8 + 4];
  float4 a0 = *(const float4*)&ar[lane * 8];
  float4 a1 = *(const float4*)&ar[lane * 8 + 4];
  float v[8];
  v[0] = x0.x + a0.x; v[1] = x0.y + a0.y; v[2] = x0.z + a0.z; v[3] = x0.w + a0.w;
  v[4] = x1.x + a1.x; v[5] = x1.y + a1.y; v[6] = x1.z + a1.z; v[7] = x1.w + a1.w;
  float s = 0.f, sq = 0.f;
#pragma unroll
  for (int i = 0; i < 8; ++i) { s += v[i]; sq += v[i] * v[i]; }
#pragma unroll
  for (int off = 32; off > 0; off >>= 1) {
    s += __shfl_xor(s, off, 64);
    sq += __shfl_xor(sq, off, 64);
  }
  const float mean = s * (1.f / 512.f);
  const float var = sq * (1.f / 512.f) - mean * mean;
  const float rstd = rsqrtf(var + 1e-5f);
  float o[8];
#pragma unroll
  for (int i = 0; i < 8; ++i) {
    const int col = lane * 8 + i;
    o[i] = (v[i] - mean) * rstd * g[col] + bt[col];
  }
  *(float4*)&xr[lane * 8]     = make_float4(o[0], o[1], o[2], o[3]);
  *(float4*)&xr[lane * 8 + 4] = make_float4(o[4], o[5], o[6], o[7]);
  *(ushort4*)&xb[(size_t)row * 512 + lane * 8]     = make_ushort4(f2bf(o[0]), f2bf(o[1]), f2bf(o[2]), f2bf(o[3]));
  *(ushort4*)&xb[(size_t)row * 512 + lane * 8 + 4] = make_ushort4(f2bf(o[4]), f2bf(o[5]), f2bf(o[6]), f2bf(o[7]));
}

__global__ __launch_bounds__(256) void ln_final(
    const float* __restrict__ x, const float* __restrict__ g,
    const float* __restrict__ bt, float* __restrict__ out)
{
  const int t = threadIdx.x, lane = t & 63, w = t >> 6;
  const int row = blockIdx.x * 4 + w;
  const float* xr = x + (size_t)row * 512;
  float4 x0 = *(const float4*)&xr[lane * 8];
  float4 x1 = *(const float4*)&xr[lane * 8 + 4];
  float v[8] = { x0.x, x0.y, x0.z, x0.w, x1.x, x1.y, x1.z, x1.w };
  float s = 0.f, sq = 0.f;
#pragma unroll
  for (int i = 0; i < 8; ++i) { s += v[i]; sq += v[i] * v[i]; }
#pragma unroll
  for (int off = 32; off > 0; off >>= 1) {
    s += __shfl_xor(s, off, 64);
    sq += __shfl_xor(sq, off, 64);
  }
  const float mean = s * (1.f / 512.f);
  const float var = sq * (1.f / 512.f) - mean * mean;
  const float rstd = rsqrtf(var + 1e-5f);
  float o[8];
#pragma unroll
  for (int i = 0; i < 8; ++i) {
    const int col = lane * 8 + i;
    o[i] = (v[i] - mean) * rstd * g[col] + bt[col];
  }
  *(float4*)&out[(size_t)row * 512 + lane * 8]     = make_float4(o[0], o[1], o[2], o[3]);
  *(float4*)&out[(size_t)row * 512 + lane * 8 + 4] = make_float4(o[4], o[5], o[6], o[7]);
}

// ---------------------------------------------------------------------------
extern "C" void kernel_launch(void* const* d_in, const int* in_sizes, int n_in,
                              void* d_out, int out_size, void* d_ws, size_t ws_size,
                              hipStream_t stream)
{
  (void)in_sizes; (void)n_in; (void)out_size; (void)ws_size;
  constexpr int Dm = 512, Lc = 4, FFc = 2048;

  const float* memory = (const float*)d_in[0];
  const float* target = (const float*)d_in[1];
  const float *saW[4], *sab[4], *caW[4], *cab[4];
  for (int j = 0; j < 4; ++j) {
    saW[j] = (const float*)d_in[2 + 2 * j];
    sab[j] = (const float*)d_in[3 + 2 * j];
    caW[j] = (const float*)d_in[10 + 2 * j];
    cab[j] = (const float*)d_in[11 + 2 * j];
  }
  const float* ffW1 = (const float*)d_in[18];
  const float* ffb1 = (const float*)d_in[19];
  const float* ffW2 = (const float*)d_in[20];
  const float* ffb2 = (const float*)d_in[21];
  const float* lng[4] = { (const float*)d_in[22], (const float*)d_in[24],
                          (const float*)d_in[26], (const float*)d_in[28] };
  const float* lnb[4] = { (const float*)d_in[23], (const float*)d_in[25],
                          (const float*)d_in[27], (const float*)d_in[29] };

  size_t off = 0;
  auto alloc = [&](size_t bytes) -> void* {
    void* p = (char*)d_ws + off;
    off += (bytes + 255) & ~(size_t)255;
    return p;
  };
  u16* WtS[4]; u16* WtC[4];
  for (int j = 0; j < 4; ++j) WtS[j] = (u16*)alloc((size_t)Lc * Dm * Dm * 2);
  for (int j = 0; j < 4; ++j) WtC[j] = (u16*)alloc((size_t)Lc * Dm * Dm * 2);
  u16* WtF1 = (u16*)alloc((size_t)Lc * Dm * FFc * 2);
  u16* WtF2 = (u16*)alloc((size_t)Lc * FFc * Dm * 2);
  float* x    = (float*)alloc((size_t)2048 * 512 * 4);
  u16*   xb   = (u16*)alloc((size_t)2048 * 512 * 2);
  u16*   memb = (u16*)alloc((size_t)2048 * 512 * 2);
  u16*   qh   = (u16*)alloc((size_t)2048 * 512 * 2);
  u16*   kh   = (u16*)alloc((size_t)2048 * 512 * 2);
  u16*   vh   = (u16*)alloc((size_t)2048 * 512 * 2);
  float* resid= (float*)alloc((size_t)2048 * 512 * 4);
  u16*   attn = (u16*)alloc((size_t)2048 * 512 * 2);
  u16*   ffh  = (u16*)alloc((size_t)2048 * 2048 * 2);
  float* KVc  = (float*)alloc((size_t)16 * 16 * 4096 * 4);
  float* zcb  = (float*)alloc((size_t)16 * 16 * 64 * 4);
  float* KVtot= (float*)alloc((size_t)16 * 4096 * 4);
  float* ztot = (float*)alloc((size_t)16 * 64 * 4);

  for (int j = 0; j < 4; ++j) {
    transpose_f2b<<<dim3(8, 8, 4), 256, 0, stream>>>(saW[j], WtS[j], Dm, Dm);
    transpose_f2b<<<dim3(8, 8, 4), 256, 0, stream>>>(caW[j], WtC[j], Dm, Dm);
  }
  transpose_f2b<<<dim3(32, 8, 4), 256, 0, stream>>>(ffW1, WtF1, Dm, FFc);
  transpose_f2b<<<dim3(8, 32, 4), 256, 0, stream>>>(ffW2, WtF2, FFc, Dm);

  cast_dual<<<512, 256, 0, stream>>>(target, x, xb);
  cast_dual<<<512, 256, 0, stream>>>(memory, nullptr, memb);

  for (int i = 0; i < Lc; ++i) {
    const size_t wo  = (size_t)i * Dm * Dm;
    const size_t wo1 = (size_t)i * Dm * FFc;
    const size_t wo2 = (size_t)i * FFc * Dm;
    // ---- causal linear self-attention ----
    gemm64<1><<<dim3(32, 24), 256, 0, stream>>>(
        xb, xb, xb, WtS[0] + wo, WtS[1] + wo, WtS[2] + wo,
        sab[0] + i * Dm, sab[1] + i * Dm, sab[2] + i * Dm,
        qh, kh, vh, 0x05, 512, 512, 3);
    lin_chunk_mfma<<<dim3(16, 16), 256, 0, stream>>>(kh, vh, KVc, zcb);
    lin_scan_exclusive<<<dim3(16, 16), 256, 0, stream>>>(KVc, zcb, KVtot, ztot);
    sa_apply_mfma<<<dim3(16, 16), 256, 0, stream>>>(qh, kh, vh, KVc, zcb, attn);
    gemm64<0><<<dim3(32, 8), 256, 0, stream>>>(
        attn, attn, attn, WtS[3] + wo, WtS[3] + wo, WtS[3] + wo,
        sab[3] + i * Dm, sab[3] + i * Dm, sab[3] + i * Dm,
        resid, resid, resid, 0, 512, 512, 3);
    ln_residual<<<512, 256, 0, stream>>>(x, resid, lng[0] + i * Dm, lnb[0] + i * Dm, xb);
    // ---- linear cross-attention ----
    gemm64<1><<<dim3(32, 24), 256, 0, stream>>>(
        xb, memb, memb, WtC[0] + wo, WtC[1] + wo, WtC[2] + wo,
        cab[0] + i * Dm, cab[1] + i * Dm, cab[2] + i * Dm,
        qh, kh, vh, 0x05, 512, 512, 3);
    lin_chunk_mfma<<<dim3(16, 16), 256, 0, stream>>>(kh, vh, KVc, zcb);
    lin_scan_exclusive<<<dim3(16, 16), 256, 0, stream>>>(KVc, zcb, KVtot, ztot);
    ca_apply_mfma<<<dim3(16, 16), 256, 0, stream>>>(qh, KVtot, ztot, attn);
    gemm64<0><<<dim3(32, 8), 256, 0, stream>>>(
        attn, attn, attn, WtC[3] + wo, WtC[3] + wo, WtC[3] + wo,
        cab[3] + i * Dm, cab[3] + i * Dm, cab[3] + i * Dm,
        resid, resid, resid, 0, 512, 512, 3);
    ln_residual<<<512, 256, 0, stream>>>(x, resid, lng[1] + i * Dm, lnb[1] + i * Dm, xb);
    // ---- FFN ----
    gemm64<1><<<dim3(32, 32), 256, 0, stream>>>(
        xb, xb, xb, WtF1 + wo1, WtF1 + wo1, WtF1 + wo1,
        ffb1 + i * FFc, ffb1 + i * FFc, ffb1 + i * FFc,
        ffh, ffh, ffh, 2, 2048, 512, 5);
    gemm64<0><<<dim3(32, 8), 256, 0, stream>>>(
        ffh, ffh, ffh, WtF2 + wo2, WtF2 + wo2, WtF2 + wo2,
        ffb2 + i * Dm, ffb2 + i * Dm, ffb2 + i * Dm,
        resid, resid, resid, 0, 512, 2048, 3);
    ln_residual<<<512, 256, 0, stream>>>(x, resid, lng[2] + i * Dm, lnb[2] + i * Dm, xb);
  }
  ln_final<<<512, 256, 0, stream>>>(x, lng[3], lnb[3], (float*)d_out);
}